// Round 7
// baseline (738.535 us; speedup 1.0000x reference)
//
#include <hip/hip_runtime.h>
#include <math.h>

// Problem constants
#define BB 8
#define TT 512
#define DD 768
#define HH 8
#define HDIM 96
#define DDDD 589824LL   // 768*768

typedef short s16x8 __attribute__((ext_vector_type(8)));
typedef float f32x4 __attribute__((ext_vector_type(4)));
typedef unsigned short u16;

__device__ inline unsigned short f2bf(float f) {
    union { float f; unsigned u; } v; v.f = f;
    unsigned u = v.u;
    unsigned r = (u + 0x7fffu + ((u >> 16) & 1u)) >> 16;
    return (unsigned short)r;
}

__device__ inline float bf2f(u16 h) {
    union { unsigned u; float f; } v; v.u = ((unsigned)h) << 16; return v.f;
}

__device__ inline float gelu_exact(float x) {
    return 0.5f * x * (1.0f + erff(x * 0.70710678118654752440f));
}

__device__ __forceinline__ void gload16(const void* g, void* l) {
    __builtin_amdgcn_global_load_lds(
        (const __attribute__((address_space(1))) unsigned int*)g,
        (__attribute__((address_space(3))) unsigned int*)l,
        16, 0, 0);
}

// Tiled activation index: 64-row tiles, k-major windows of 8.
// elem (m, k) of a [M][ldn] matrix -> ((m/64)*(ldn/8) + k/8)*512 + (m%64)*8 + k%8
__device__ __forceinline__ long long tix(int m, int k, int ldn) {
    return ((long long)(m >> 6) * (ldn >> 3) + (k >> 3)) * 512 + ((m & 63) << 3) + (k & 7);
}

// ---------------------------------------------------------------------------
// Weight convert: f32 -> bf16, written in k-major TILED layout
//   B'[ntile128][kw=K/8][row128][8]  (per matrix; experts consecutive).
// tp_wq/wk/wv are interleaved into one [2304][768] matrix per expert.
// ---------------------------------------------------------------------------
#define CUM1  7077888LL
#define CUM2  9437184LL
#define CUM3  11796480LL
#define CUM4  14155776LL
#define CUM5  16515072LL
#define CUM6  18874368LL
#define CUM7  20643840LL
#define CUM8  21233664LL
#define CUM9  23592960LL
#define CUM10 25952256LL

__global__ __launch_bounds__(256) void cvt_kernel(
    const float* __restrict__ s0, const float* __restrict__ s1,
    const float* __restrict__ s2, const float* __restrict__ s3,
    const float* __restrict__ s4, const float* __restrict__ s5,
    const float* __restrict__ s6, const float* __restrict__ s7,
    const float* __restrict__ s8, const float* __restrict__ s9,
    u16* __restrict__ dpool)
{
    long long g = ((long long)blockIdx.x * 256 + threadIdx.x) * 8;
    if (g >= CUM10) return;
    const float* s; long long i, base; int n, k, K = 768;
    const long long SZQKV = 2304LL * 768;
    if (g < CUM1) {                 // sp_wqkv: 4 x [2304][768]
        s = s0; i = g;
        long long e = i / SZQKV, r = i - e * SZQKV;
        n = (int)(r / 768); k = (int)(r % 768); base = e * 3 * DDDD;
    } else if (g < CUM2) {          // sp_wo: 4 x [768][768]
        s = s1; i = g - CUM1;
        long long e = i / DDDD, r = i - e * DDDD;
        n = (int)(r / 768); k = (int)(r % 768); base = CUM1 + e * DDDD;
    } else if (g < CUM5) {          // tp_wq/wk/wv -> interleaved [2304][768]
        int tp = (g < CUM3) ? 0 : (g < CUM4) ? 1 : 2;
        s = (tp == 0) ? s2 : (tp == 1) ? s3 : s4;
        i = g - ((tp == 0) ? CUM2 : (tp == 1) ? CUM3 : CUM4);
        long long e = i / DDDD, r = i - e * DDDD;
        n = tp * 768 + (int)(r / 768); k = (int)(r % 768);
        base = CUM2 + e * 3 * DDDD;
    } else if (g < CUM6) {          // tp_wo: 4 x [768][768]
        s = s5; i = g - CUM5;
        long long e = i / DDDD, r = i - e * DDDD;
        n = (int)(r / 768); k = (int)(r % 768); base = CUM5 + e * DDDD;
    } else if (g < CUM7) {          // c_wqkv: [2304][768]
        s = s6; i = g - CUM6;
        n = (int)(i / 768); k = (int)(i % 768); base = CUM6;
    } else if (g < CUM8) {          // c_wo: [768][768]
        s = s7; i = g - CUM7;
        n = (int)(i / 768); k = (int)(i % 768); base = CUM7;
    } else if (g < CUM9) {          // m_w1: [3072][768]
        s = s8; i = g - CUM8;
        n = (int)(i / 768); k = (int)(i % 768); base = CUM8;
    } else {                        // m_w2: [768][3072]
        s = s9; i = g - CUM9;
        n = (int)(i / 3072); k = (int)(i % 3072); base = CUM9; K = 3072;
    }
    float4 a = *(const float4*)(s + i);
    float4 b = *(const float4*)(s + i + 4);
    s16x8 o;
    o[0] = f2bf(a.x); o[1] = f2bf(a.y); o[2] = f2bf(a.z); o[3] = f2bf(a.w);
    o[4] = f2bf(b.x); o[5] = f2bf(b.y); o[6] = f2bf(b.z); o[7] = f2bf(b.w);
    long long d = base + (((long long)(n >> 7) * (K >> 3) + (k >> 3)) << 10) + ((n & 127) << 3);
    *(s16x8*)(dpool + d) = o;
}

// pack temporal biases [4][2304] = bq|bk|bv
__global__ __launch_bounds__(256) void pack_tpb_kernel(
    const float* __restrict__ bq, const float* __restrict__ bk,
    const float* __restrict__ bv, float* __restrict__ dst)
{
    int t = blockIdx.x * 256 + threadIdx.x;
    if (t >= 4 * 2304) return;
    int e = t / 2304, n = t - e * 2304;
    float v = (n < 768) ? bq[e * 768 + n]
            : (n < 1536) ? bk[e * 768 + n - 768]
            : bv[e * 768 + n - 1536];
    dst[t] = v;
}

// ---------------------------------------------------------------------------
// bf16 GEMM: C[z] = A[z] * B^T (+bias) (gelu?) (+resid)
//   A TILED [mtile64][kw][64][8] per batch; B TILED [ntile128][kw][128][8].
//   Tile 64x128 (MxN), BK=32, 4 waves each 32x64 via 2x4 MFMA 16x16x32.
//   6-SLAB RING, DEPTH 5: prologue issues slabs 0..4; iter kt waits
//   vmcnt(12) [slab kt landed, kt+1..kt+4 in flight], one s_barrier,
//   stages slab kt+5 into the buffer vacated at kt-1. Counted vmcnt only.
//   XCD-CHUNKED SWIZZLE: x-fastest linearization split into 8 contiguous
//   chunks, one per XCD -> blocks sharing an A-strip / weight panel hit
//   the same L2 (FETCH ~ unique bytes).
//   LDS 72 KB -> 2 blocks/CU.
//   OUT_MODE: 0 f32 row-major, 1 bf16 row-major, 2 bf16 tiled.
//   RES_MODE: 0 none, 1 f32 row-major, 2 bf16 tiled.
//   Requires M=512, N%128==0, K%32==0, K/32 >= 6, grid size %8 == 0.
// ---------------------------------------------------------------------------
#define SLABA 2048    // 64*32 elems = 4 KB
#define SLABB 4096    // 128*32 elems = 8 KB

template<int OUT_MODE, int RES_MODE>
__global__ __launch_bounds__(256) void gemm_bf16_kernel(
    const u16* __restrict__ A, long long sAb,
    const u16* __restrict__ B, const int* __restrict__ bidx, long long sBexp,
    void* __restrict__ Cv, long long sCb, int ldc,
    const float* __restrict__ bias, long long sBiasExp,
    const void* __restrict__ residv, long long sResB, int ldr,
    int act, int N, int K)
{
    // ---- XCD-chunked bijective swizzle (x-fastest linear order) ----
    int nbx = gridDim.x, nby = gridDim.y;
    int nblk = nbx * nby * (int)gridDim.z;
    int lin = blockIdx.x + nbx * (blockIdx.y + nby * blockIdx.z);
    int q = nblk >> 3, r = nblk & 7;
    int xcd = lin & 7, pos = lin >> 3;
    int nl = (xcd < r ? xcd * (q + 1) : r * (q + 1) + (xcd - r) * q) + pos;
    int bx = nl % nbx; int t1 = nl / nbx; int by = t1 % nby; int bz = t1 / nby;

    int zb = bz;
    int kw8 = K >> 3;
    const u16* Ab = A + zb * sAb + (long long)by * kw8 * 512;
    const u16* Bb = B + (bidx ? (long long)bidx[zb] * sBexp : 0)
                      + (long long)bx * kw8 * 1024;
    const float* biasb = bias ? (bias + (bidx ? (long long)bidx[zb] * sBiasExp : 0)) : nullptr;

    __shared__ __align__(16) u16 As[6][SLABA];   // 24 KB
    __shared__ __align__(16) u16 Bs[6][SLABB];   // 48 KB

    int tid = threadIdx.x;
    int wave = tid >> 6, lane = tid & 63;
    int wr = wave >> 1, wc = wave & 1;
    int lrow = lane & 15, lkg = lane >> 4;

    f32x4 acc[2][4];
    #pragma unroll
    for (int i = 0; i < 2; i++)
        #pragma unroll
        for (int j = 0; j < 4; j++)
            acc[i][j] = (f32x4){0.f, 0.f, 0.f, 0.f};

    const u16* agt = Ab + tid * 8;
    const u16* bgt = Bb + tid * 8;
    u16* al  = (u16*)As + tid * 8;
    u16* bl0 = (u16*)Bs + tid * 8;
    u16* bl1 = (u16*)Bs + (tid + 256) * 8;

    auto stage = [&](int slab, int buf) {
        gload16(agt + slab * SLABA,        al  + buf * SLABA);
        gload16(bgt + slab * SLABB,        bl0 + buf * SLABB);
        gload16(bgt + slab * SLABB + 2048, bl1 + buf * SLABB);
    };

    int nK = K >> 5;
    stage(0, 0); stage(1, 1); stage(2, 2); stage(3, 3); stage(4, 4);

    int cur = 0, nxt = 5;
    for (int kt = 0; kt < nK; ++kt) {
        int infl = nK - 1 - kt; if (infl > 4) infl = 4;
        switch (infl) {
            case 4: asm volatile("s_waitcnt vmcnt(12)" ::: "memory"); break;
            case 3: asm volatile("s_waitcnt vmcnt(9)" ::: "memory"); break;
            case 2: asm volatile("s_waitcnt vmcnt(6)" ::: "memory"); break;
            case 1: asm volatile("s_waitcnt vmcnt(3)" ::: "memory"); break;
            default: asm volatile("s_waitcnt vmcnt(0)" ::: "memory"); break;
        }
        __builtin_amdgcn_s_barrier();        // all waves' slab-kt loads landed;
                                             // all waves done reading slab kt-1
        __builtin_amdgcn_sched_barrier(0);
        if (kt + 5 < nK) stage(kt + 5, nxt);

        const u16* Asb = &As[cur][0];
        const u16* Bsb = &Bs[cur][0];
        s16x8 af[2], bf[4];
        #pragma unroll
        for (int i = 0; i < 2; ++i)
            af[i] = *(const s16x8*)&Asb[((lkg) * 64 + wr * 32 + i * 16 + lrow) * 8];
        #pragma unroll
        for (int j = 0; j < 4; ++j)
            bf[j] = *(const s16x8*)&Bsb[((lkg) * 128 + wc * 64 + j * 16 + lrow) * 8];
        #pragma unroll
        for (int i = 0; i < 2; ++i)
            #pragma unroll
            for (int j = 0; j < 4; ++j)
                acc[i][j] = __builtin_amdgcn_mfma_f32_16x16x32_bf16(af[i], bf[j], acc[i][j], 0, 0, 0);
        cur = (cur + 1 == 6) ? 0 : cur + 1;
        nxt = (nxt + 1 == 6) ? 0 : nxt + 1;
    }

    // epilogue: C/D layout col=lane&15, row=(lane>>4)*4+reg
    int n0 = bx * 128;
    int m0 = by * 64;
    float* Cf = (float*)Cv + zb * sCb;
    u16* Ch = (u16*)Cv + zb * sCb;
    const float* Rf = (const float*)residv + zb * sResB;
    const u16* Rh = (const u16*)residv + zb * sResB;
    int col16 = lane & 15;
    int rq = (lane >> 4) * 4;
    #pragma unroll
    for (int j = 0; j < 4; ++j) {
        int n = n0 + wc * 64 + j * 16 + col16;
        float bv = biasb ? biasb[n] : 0.0f;
        #pragma unroll
        for (int i = 0; i < 2; ++i) {
            #pragma unroll
            for (int r2 = 0; r2 < 4; ++r2) {
                int m = m0 + wr * 32 + i * 16 + rq + r2;
                float v = acc[i][j][r2] + bv;
                if (act == 1) v = gelu_exact(v);
                if (RES_MODE == 1) v += Rf[(long long)m * ldr + n];
                if (RES_MODE == 2) v += bf2f(Rh[tix(m, n, ldr)]);
                if (OUT_MODE == 0) Cf[(long long)m * ldc + n] = v;
                if (OUT_MODE == 1) Ch[(long long)m * ldc + n] = f2bf(v);
                if (OUT_MODE == 2) Ch[tix(m, n, ldc)] = f2bf(v);
            }
        }
    }
}

// ---------------------------------------------------------------------------
// Fused flash attention (bf16): O = softmax(scale * Q K^T [causal]) V.
// QKV bf16 ROW-MAJOR [B][T][3*D]; Out bf16 TILED (A-layout for next GEMM).
// Grid (T/64, B*H), 256 threads = 4 waves, each wave owns 16 query rows.
// ---------------------------------------------------------------------------
__global__ __launch_bounds__(256, 2) void attn_kernel(
    const u16* __restrict__ QKV, u16* __restrict__ Out,
    int causal, float scale)
{
    int qt = blockIdx.x;
    int bh = blockIdx.y;
    int b = bh >> 3;
    int h = bh & 7;
    const u16* Qb = QKV + (long long)b * TT * 3 * DD + (long long)h * HDIM;
    const u16* Kb = Qb + DD;
    const u16* Vb = Qb + 2 * DD;
    u16* Ob = Out + (long long)b * TT * DD;   // tiled within batch

    __shared__ __align__(16) u16 Qs[64 * 104];  // [qrow][d], stride 104
    __shared__ __align__(16) u16 Ks[64 * 104];
    __shared__ __align__(16) u16 Vs[96 * 72];   // [d][krow], stride 72
    __shared__ __align__(16) u16 Ps[64 * 72];   // [qrow][krow]

    int tid = threadIdx.x;
    int wave = tid >> 6;
    int lane = tid & 63;
    int col16 = lane & 15;
    int lkg = lane >> 4;
    int lk = lkg * 8;
    int m0 = qt * 64;

    // ---- stage Q tile 64x96 bf16 ----
    #pragma unroll
    for (int it = 0; it < 3; ++it) {
        int s = tid + it * 256;
        int r = s / 12, c8 = (s % 12) * 8;
        *(s16x8*)&Qs[r * 104 + c8] = *(const s16x8*)(Qb + (long long)(m0 + r) * (3 * DD) + c8);
    }
    __syncthreads();

    s16x8 qf[3];
    #pragma unroll
    for (int kk = 0; kk < 3; ++kk)
        qf[kk] = *(const s16x8*)&Qs[(wave * 16 + col16) * 104 + kk * 32 + lk];

    // ---- QK^T ----
    f32x4 acc[32];
    #pragma unroll
    for (int n = 0; n < 32; ++n) acc[n] = (f32x4){0.f, 0.f, 0.f, 0.f};

    #pragma unroll
    for (int kt = 0; kt < 8; ++kt) {
        #pragma unroll
        for (int it = 0; it < 3; ++it) {
            int s = tid + it * 256;
            int r = s / 12, c8 = (s % 12) * 8;
            *(s16x8*)&Ks[r * 104 + c8] = *(const s16x8*)(Kb + (long long)(kt * 64 + r) * (3 * DD) + c8);
        }
        __syncthreads();
        #pragma unroll
        for (int kk = 0; kk < 3; ++kk) {
            #pragma unroll
            for (int j = 0; j < 4; ++j) {
                s16x8 bfr = *(const s16x8*)&Ks[(j * 16 + col16) * 104 + kk * 32 + lk];
                acc[kt * 4 + j] = __builtin_amdgcn_mfma_f32_16x16x32_bf16(qf[kk], bfr, acc[kt * 4 + j], 0, 0, 0);
            }
        }
        __syncthreads();
    }

    // ---- softmax (registers + shfl only) ----
    int rowbase = m0 + wave * 16 + lkg * 4;
    float mx[4];
    #pragma unroll
    for (int r = 0; r < 4; ++r) mx[r] = -3.0e38f;
    #pragma unroll
    for (int n = 0; n < 32; ++n) {
        int colg = n * 16 + col16;
        #pragma unroll
        for (int r = 0; r < 4; ++r) {
            float v = acc[n][r] * scale;
            if (causal && colg > rowbase + r) v = -3.0e38f;
            acc[n][r] = v;
            mx[r] = fmaxf(mx[r], v);
        }
    }
    #pragma unroll
    for (int m = 1; m <= 8; m <<= 1)
        #pragma unroll
        for (int r = 0; r < 4; ++r)
            mx[r] = fmaxf(mx[r], __shfl_xor(mx[r], m, 64));

    float sum[4] = {0.f, 0.f, 0.f, 0.f};
    #pragma unroll
    for (int n = 0; n < 32; ++n) {
        #pragma unroll
        for (int r = 0; r < 4; ++r) {
            float e = __expf(acc[n][r] - mx[r]);
            acc[n][r] = e;
            sum[r] += e;
        }
    }
    #pragma unroll
    for (int m = 1; m <= 8; m <<= 1)
        #pragma unroll
        for (int r = 0; r < 4; ++r)
            sum[r] += __shfl_xor(sum[r], m, 64);
    float inv[4];
    #pragma unroll
    for (int r = 0; r < 4; ++r) inv[r] = 1.0f / sum[r];

    // ---- PV ----
    f32x4 oacc[6];
    #pragma unroll
    for (int j = 0; j < 6; ++j) oacc[j] = (f32x4){0.f, 0.f, 0.f, 0.f};

    #pragma unroll
    for (int kt = 0; kt < 8; ++kt) {
        __syncthreads();
        #pragma unroll
        for (int j = 0; j < 4; ++j) {
            #pragma unroll
            for (int r = 0; r < 4; ++r)
                Ps[(wave * 16 + lkg * 4 + r) * 72 + j * 16 + col16] = f2bf(acc[kt * 4 + j][r]);
        }
        #pragma unroll
        for (int it = 0; it < 3; ++it) {
            int s = tid + it * 256;
            int key = s / 12, c8 = (s % 12) * 8;
            s16x8 v = *(const s16x8*)(Vb + (long long)(kt * 64 + key) * (3 * DD) + c8);
            #pragma unroll
            for (int e = 0; e < 8; ++e)
                Vs[(c8 + e) * 72 + key] = (u16)v[e];
        }
        __syncthreads();
        #pragma unroll
        for (int kk = 0; kk < 2; ++kk) {
            s16x8 pf = *(const s16x8*)&Ps[(wave * 16 + col16) * 72 + kk * 32 + lk];
            #pragma unroll
            for (int j = 0; j < 6; ++j) {
                s16x8 vf = *(const s16x8*)&Vs[(j * 16 + col16) * 72 + kk * 32 + lk];
                oacc[j] = __builtin_amdgcn_mfma_f32_16x16x32_bf16(pf, vf, oacc[j], 0, 0, 0);
            }
        }
    }

    // ---- epilogue: write TILED ----
    int rquad = lkg * 4;
    #pragma unroll
    for (int j = 0; j < 6; ++j) {
        int d = h * 96 + j * 16 + col16;
        #pragma unroll
        for (int r = 0; r < 4; ++r) {
            int row = m0 + wave * 16 + rquad + r;
            Ob[tix(row, d, DD)] = f2bf(oacc[j][r] * inv[r]);
        }
    }
}

// ---------------------------------------------------------------------------
// LayerNorm over last dim (768), bf16 TILED output. One block per row.
// ---------------------------------------------------------------------------
__global__ __launch_bounds__(256) void ln_kernel(
    const float* __restrict__ x, const float* __restrict__ g,
    const float* __restrict__ b, u16* __restrict__ out)
{
    long long row = blockIdx.x;
    const float* xr = x + row * DD;
    u16* ob = out + (row >> 9) * ((long long)TT * DD);  // batch base
    int m = (int)(row & 511);
    int t = threadIdx.x;
    float vals[3];
    float s = 0.f, ss = 0.f;
    #pragma unroll
    for (int i = 0; i < 3; i++) {
        float v = xr[t + i * 256];
        vals[i] = v; s += v; ss += v * v;
    }
    __shared__ float rs[256], rss[256];
    rs[t] = s; rss[t] = ss; __syncthreads();
    for (int k = 128; k > 0; k >>= 1) {
        if (t < k) { rs[t] += rs[t + k]; rss[t] += rss[t + k]; }
        __syncthreads();
    }
    float mean = rs[0] * (1.0f / DD);
    float var = rss[0] * (1.0f / DD) - mean * mean;
    float inv = rsqrtf(var + 1e-5f);
    #pragma unroll
    for (int i = 0; i < 3; i++) {
        int d = t + i * 256;
        ob[tix(m, d, DD)] = f2bf((vals[i] - mean) * inv * g[d] + b[d]);
    }
}

// ---------------------------------------------------------------------------
// Router part 1: partial column sums of x over T.
// ---------------------------------------------------------------------------
__global__ __launch_bounds__(256) void mean_part_kernel(
    const float* __restrict__ x, float* __restrict__ part)
{
    int b = blockIdx.x, dseg = blockIdx.y, rc = blockIdx.z;
    int d = dseg * 256 + threadIdx.x;
    const float* xb = x + (long long)b * TT * DD;
    float s = 0.f;
    int r0 = rc * 64;
    for (int r = r0; r < r0 + 64; ++r) s += xb[(long long)r * DD + d];
    part[((long long)b * 8 + rc) * DD + d] = s;
}

// ---------------------------------------------------------------------------
// Router part 2.
// ---------------------------------------------------------------------------
__global__ __launch_bounds__(128) void router_kernel(
    const float* __restrict__ part, const float* __restrict__ w1,
    const float* __restrict__ b1, const float* __restrict__ w2,
    const float* __restrict__ b2, int* __restrict__ idx)
{
    int b = blockIdx.x, t = threadIdx.x;
    __shared__ float xm[DD];
    __shared__ float h[128];
    __shared__ float logits[8];
    for (int i = t; i < DD; i += 128) {
        float s = 0.f;
        for (int rc = 0; rc < 8; ++rc) s += part[((long long)b * 8 + rc) * DD + i];
        xm[i] = s * (1.0f / TT);
    }
    __syncthreads();
    {
        float s = b1[t];
        const float* w = w1 + (long long)t * DD;
        for (int d = 0; d < DD; ++d) s += xm[d] * w[d];
        h[t] = gelu_exact(s);
    }
    __syncthreads();
    if (t < 8) {
        float s = b2[t];
        const float* w = w2 + t * 128;
        for (int d = 0; d < 128; ++d) s += h[d] * w[d];
        logits[t] = s;
    }
    __syncthreads();
    if (t == 0) {
        int bsix = 0;
        for (int i = 1; i < 4; i++) if (logits[i] > logits[bsix]) bsix = i;
        int btix = 4;
        for (int i = 5; i < 8; i++) if (logits[i] > logits[btix]) btix = i;
        idx[b] = bsix;
        idx[b + BB] = btix - 4;
    }
}

// ---------------------------------------------------------------------------
static void run_gemm2(hipStream_t stream,
    const u16* A, long long sAb,
    const u16* B, const int* bidx, long long sBexp,
    void* C, long long sCb, int ldc,
    const float* bias, long long sBiasExp,
    const void* resid, long long sResB, int ldr,
    int act, int N, int K, int outmode, int resmode)
{
    dim3 grid(N / 128, 8, BB);
    if (outmode == 1)
        gemm_bf16_kernel<1, 0><<<grid, 256, 0, stream>>>(A, sAb, B, bidx, sBexp,
            C, sCb, ldc, bias, sBiasExp, resid, sResB, ldr, act, N, K);
    else if (outmode == 2 && resmode == 0)
        gemm_bf16_kernel<2, 0><<<grid, 256, 0, stream>>>(A, sAb, B, bidx, sBexp,
            C, sCb, ldc, bias, sBiasExp, resid, sResB, ldr, act, N, K);
    else if (outmode == 2)
        gemm_bf16_kernel<2, 2><<<grid, 256, 0, stream>>>(A, sAb, B, bidx, sBexp,
            C, sCb, ldc, bias, sBiasExp, resid, sResB, ldr, act, N, K);
    else
        gemm_bf16_kernel<0, 1><<<grid, 256, 0, stream>>>(A, sAb, B, bidx, sBexp,
            C, sCb, ldc, bias, sBiasExp, resid, sResB, ldr, act, N, K);
}

extern "C" void kernel_launch(void* const* d_in, const int* in_sizes, int n_in,
                              void* d_out, int out_size, void* d_ws, size_t ws_size,
                              hipStream_t stream)
{
    const float* x       = (const float*)d_in[0];
    const float* rw1     = (const float*)d_in[1];
    const float* rb1     = (const float*)d_in[2];
    const float* rw2     = (const float*)d_in[3];
    const float* rb2     = (const float*)d_in[4];
    const float* gs      = (const float*)d_in[5];
    const float* bs      = (const float*)d_in[6];
    const float* gt      = (const float*)d_in[7];
    const float* btt     = (const float*)d_in[8];
    const float* gm      = (const float*)d_in[9];
    const float* bm      = (const float*)d_in[10];
    const float* sp_wqkv = (const float*)d_in[11];
    const float* sp_bqkv = (const float*)d_in[12];
    const float* sp_wo   = (const float*)d_in[13];
    const float* sp_bo   = (const float*)d_in[14];
    const float* tp_wq   = (const float*)d_in[15];
    const float* tp_bq   = (const float*)d_in[16];
    const float* tp_wk   = (const float*)d_in[17];
    const float* tp_bk   = (const float*)d_in[18];
    const float* tp_wv   = (const float*)d_in[19];
    const float* tp_bv   = (const float*)d_in[20];
    const float* tp_wo   = (const float*)d_in[21];
    const float* tp_bo   = (const float*)d_in[22];
    const float* c_wqkv  = (const float*)d_in[23];
    const float* c_bqkv  = (const float*)d_in[24];
    const float* c_wo    = (const float*)d_in[25];
    const float* c_bo    = (const float*)d_in[26];
    const float* m_w1    = (const float*)d_in[27];
    const float* m_b1    = (const float*)d_in[28];
    const float* m_w2    = (const float*)d_in[29];
    const float* m_b2    = (const float*)d_in[30];
    float* out = (float*)d_out;

    float* ws = (float*)d_ws;
    size_t o = 0;
    float* part  = ws + o; o += (size_t)BB * 8 * DD;
    int*   idx   = (int*)(ws + o); o += 16;
    float* tpb   = ws + o; o += 4 * 2304;                     // packed temporal bias
    float* x1b   = ws + o; o += (size_t)4096 * DD;            // f32 (x + fused)
    u16* xnb   = (u16*)(ws + o); o += (size_t)4096 * DD / 2;  // LN out (tiled bf16)
    u16* tmp1b = (u16*)(ws + o); o += (size_t)4096 * DD / 2;  // attn out (tiled)
    u16* tmp2b = (u16*)(ws + o); o += (size_t)4096 * DD / 2;  // LN for mlp (tiled)
    u16* soutb = (u16*)(ws + o); o += (size_t)4096 * DD / 2;  // spatial_out (tiled)
    u16* toutb = (u16*)(ws + o); o += (size_t)4096 * DD / 2;  // temporal_out (tiled)
    u16* qkvb  = (u16*)(ws + o); o += (size_t)4096 * 2304 / 2;// q|k|v row-major bf16
    u16* yb    = (u16*)(ws + o); o += (size_t)4096 * 3072 / 2;// mlp hidden (tiled)
    u16* wpool = (u16*)(ws + o); o += (size_t)CUM10 / 2;      // bf16 weights (tiled)

    u16* w_sp_qkv = wpool;
    u16* w_sp_wo  = wpool + CUM1;
    u16* w_tp_qkv = wpool + CUM2;   // interleaved [e][2304][768] tiled
    u16* w_tp_o   = wpool + CUM5;
    u16* w_c_qkv  = wpool + CUM6;
    u16* w_c_wo   = wpool + CUM7;
    u16* w_m1     = wpool + CUM8;
    u16* w_m2     = wpool + CUM9;

    int* idx_s = idx;
    int* idx_t = idx + BB;

    const long long sTD  = (long long)TT * DD;       // 512*768
    const long long sT3D = (long long)TT * 3 * DD;   // 512*2304
    const long long sT4D = (long long)TT * 4 * DD;   // 512*3072
    const float qk_scale = 1.0f / sqrtf((float)HDIM);

    // ---- weight convert (f32 -> bf16 tiled) + temporal bias pack ----
    cvt_kernel<<<(int)((CUM10 / 8 + 255) / 256), 256, 0, stream>>>(
        sp_wqkv, sp_wo, tp_wq, tp_wk, tp_wv, tp_wo, c_wqkv, c_wo, m_w1, m_w2, wpool);
    pack_tpb_kernel<<<36, 256, 0, stream>>>(tp_bq, tp_bk, tp_bv, tpb);

    // ---- router ----
    mean_part_kernel<<<dim3(BB, 3, 8), 256, 0, stream>>>(x, part);
    router_kernel<<<BB, 128, 0, stream>>>(part, rw1, rb1, rw2, rb2, idx);

    // ---- spatial branch ----
    ln_kernel<<<4096, 256, 0, stream>>>(x, gs, bs, xnb);
    // qkv = xn @ sp_wqkv[idx_s]^T + sp_bqkv[idx_s]  -> row-major for attn
    run_gemm2(stream, xnb, sTD, w_sp_qkv, idx_s, 3 * DDDD,
              qkvb, sT3D, 3 * DD, sp_bqkv, 3 * DD, nullptr, 0, 0,
              0, 3 * DD, DD, 1, 0);
    attn_kernel<<<dim3(TT / 64, BB * HH), 256, 0, stream>>>(qkvb, tmp1b, 0, qk_scale);
    // spatial_out = O @ sp_wo[idx_s]^T + sp_bo[idx_s]  -> tiled
    run_gemm2(stream, tmp1b, sTD, w_sp_wo, idx_s, DDDD,
              soutb, sTD, DD, sp_bo, DD, nullptr, 0, 0,
              0, DD, DD, 2, 0);

    // ---- temporal branch ----
    ln_kernel<<<4096, 256, 0, stream>>>(x, gt, btt, xnb);
    run_gemm2(stream, xnb, sTD, w_tp_qkv, idx_t, 3 * DDDD,
              qkvb, sT3D, 3 * DD, tpb, 3 * DD, nullptr, 0, 0,
              0, 3 * DD, DD, 1, 0);
    attn_kernel<<<dim3(TT / 64, BB * HH), 256, 0, stream>>>(qkvb, tmp1b, 1, qk_scale);
    // temporal_out = xt + O @ tp_wo[idx_t]^T + tp_bo[idx_t]  (tiled, tiled resid)
    run_gemm2(stream, tmp1b, sTD, w_tp_o, idx_t, DDDD,
              toutb, sTD, DD, tp_bo, DD, xnb, sTD, DD,
              0, DD, DD, 2, 2);

    // ---- cross attention ----
    run_gemm2(stream, soutb, sTD, w_c_qkv, nullptr, 0,
              qkvb, sT3D, 3 * DD, c_bqkv, 0, nullptr, 0, 0,
              0, DD, DD, 1, 0);
    // rows 768..2303 of c_wqkv = tiles 6.. -> offset DDDD elems
    run_gemm2(stream, toutb, sTD, w_c_qkv + DDDD, nullptr, 0,
              qkvb + DD, sT3D, 3 * DD, c_bqkv + DD, 0, nullptr, 0, 0,
              0, 2 * DD, DD, 1, 0);
    attn_kernel<<<dim3(TT / 64, BB * HH), 256, 0, stream>>>(qkvb, tmp1b, 0, qk_scale);
    // x1 = x + (fused_attn @ cross_wo^T + cross_bo)   (f32 out, f32 resid)
    run_gemm2(stream, tmp1b, sTD, w_c_wo, nullptr, 0,
              x1b, sTD, DD, c_bo, 0, x, sTD, DD,
              0, DD, DD, 0, 1);

    // ---- MLP ----
    ln_kernel<<<4096, 256, 0, stream>>>(x1b, gm, bm, tmp2b);
    // y = gelu(ln @ mlp_w1^T + b1) -> tiled bf16
    run_gemm2(stream, tmp2b, sTD, w_m1, nullptr, 0,
              yb, sT4D, 4 * DD, m_b1, 0, nullptr, 0, 0,
              1, 4 * DD, DD, 2, 0);
    // out = x1 + y @ mlp_w2^T + b2   (f32 out, f32 resid)
    run_gemm2(stream, yb, sT4D, w_m2, nullptr, 0,
              out, sTD, DD, m_b2, 0, x1b, sTD, DD,
              0, DD, 4 * DD, 0, 1);
}

// Round 8
// 624.981 us; speedup vs baseline: 1.1817x; 1.1817x over previous
//
#include <hip/hip_runtime.h>
#include <math.h>

// Problem constants
#define BB 8
#define TT 512
#define DD 768
#define HH 8
#define HDIM 96
#define DDDD 589824LL   // 768*768

typedef short s16x8 __attribute__((ext_vector_type(8)));
typedef float f32x4 __attribute__((ext_vector_type(4)));
typedef unsigned short u16;

__device__ inline unsigned short f2bf(float f) {
    union { float f; unsigned u; } v; v.f = f;
    unsigned u = v.u;
    unsigned r = (u + 0x7fffu + ((u >> 16) & 1u)) >> 16;
    return (unsigned short)r;
}

__device__ inline float bf2f(u16 h) {
    union { unsigned u; float f; } v; v.u = ((unsigned)h) << 16; return v.f;
}

__device__ inline float gelu_exact(float x) {
    return 0.5f * x * (1.0f + erff(x * 0.70710678118654752440f));
}

__device__ __forceinline__ void gload16(const void* g, void* l) {
    __builtin_amdgcn_global_load_lds(
        (const __attribute__((address_space(1))) unsigned int*)g,
        (__attribute__((address_space(3))) unsigned int*)l,
        16, 0, 0);
}

// Tiled activation index: 64-row tiles, k-major windows of 8.
// elem (m, k) of a [M][ldn] matrix -> ((m/64)*(ldn/8) + k/8)*512 + (m%64)*8 + k%8
__device__ __forceinline__ long long tix(int m, int k, int ldn) {
    return ((long long)(m >> 6) * (ldn >> 3) + (k >> 3)) * 512 + ((m & 63) << 3) + (k & 7);
}

// ---------------------------------------------------------------------------
// Weight convert: f32 -> bf16, written in k-major TILED layout
//   B'[ntile128][kw=K/8][row128][8]  (per matrix; experts consecutive).
// tp_wq/wk/wv are interleaved into one [2304][768] matrix per expert.
// ---------------------------------------------------------------------------
#define CUM1  7077888LL
#define CUM2  9437184LL
#define CUM3  11796480LL
#define CUM4  14155776LL
#define CUM5  16515072LL
#define CUM6  18874368LL
#define CUM7  20643840LL
#define CUM8  21233664LL
#define CUM9  23592960LL
#define CUM10 25952256LL

__global__ __launch_bounds__(256) void cvt_kernel(
    const float* __restrict__ s0, const float* __restrict__ s1,
    const float* __restrict__ s2, const float* __restrict__ s3,
    const float* __restrict__ s4, const float* __restrict__ s5,
    const float* __restrict__ s6, const float* __restrict__ s7,
    const float* __restrict__ s8, const float* __restrict__ s9,
    u16* __restrict__ dpool)
{
    long long g = ((long long)blockIdx.x * 256 + threadIdx.x) * 8;
    if (g >= CUM10) return;
    const float* s; long long i, base; int n, k, K = 768;
    const long long SZQKV = 2304LL * 768;
    if (g < CUM1) {                 // sp_wqkv: 4 x [2304][768]
        s = s0; i = g;
        long long e = i / SZQKV, r = i - e * SZQKV;
        n = (int)(r / 768); k = (int)(r % 768); base = e * 3 * DDDD;
    } else if (g < CUM2) {          // sp_wo: 4 x [768][768]
        s = s1; i = g - CUM1;
        long long e = i / DDDD, r = i - e * DDDD;
        n = (int)(r / 768); k = (int)(r % 768); base = CUM1 + e * DDDD;
    } else if (g < CUM5) {          // tp_wq/wk/wv -> interleaved [2304][768]
        int tp = (g < CUM3) ? 0 : (g < CUM4) ? 1 : 2;
        s = (tp == 0) ? s2 : (tp == 1) ? s3 : s4;
        i = g - ((tp == 0) ? CUM2 : (tp == 1) ? CUM3 : CUM4);
        long long e = i / DDDD, r = i - e * DDDD;
        n = tp * 768 + (int)(r / 768); k = (int)(r % 768);
        base = CUM2 + e * 3 * DDDD;
    } else if (g < CUM6) {          // tp_wo: 4 x [768][768]
        s = s5; i = g - CUM5;
        long long e = i / DDDD, r = i - e * DDDD;
        n = (int)(r / 768); k = (int)(r % 768); base = CUM5 + e * DDDD;
    } else if (g < CUM7) {          // c_wqkv: [2304][768]
        s = s6; i = g - CUM6;
        n = (int)(i / 768); k = (int)(i % 768); base = CUM6;
    } else if (g < CUM8) {          // c_wo: [768][768]
        s = s7; i = g - CUM7;
        n = (int)(i / 768); k = (int)(i % 768); base = CUM7;
    } else if (g < CUM9) {          // m_w1: [3072][768]
        s = s8; i = g - CUM8;
        n = (int)(i / 768); k = (int)(i % 768); base = CUM8;
    } else {                        // m_w2: [768][3072]
        s = s9; i = g - CUM9;
        n = (int)(i / 3072); k = (int)(i % 3072); base = CUM9; K = 3072;
    }
    float4 a = *(const float4*)(s + i);
    float4 b = *(const float4*)(s + i + 4);
    s16x8 o;
    o[0] = f2bf(a.x); o[1] = f2bf(a.y); o[2] = f2bf(a.z); o[3] = f2bf(a.w);
    o[4] = f2bf(b.x); o[5] = f2bf(b.y); o[6] = f2bf(b.z); o[7] = f2bf(b.w);
    long long d = base + (((long long)(n >> 7) * (K >> 3) + (k >> 3)) << 10) + ((n & 127) << 3);
    *(s16x8*)(dpool + d) = o;
}

// pack temporal biases [4][2304] = bq|bk|bv
__global__ __launch_bounds__(256) void pack_tpb_kernel(
    const float* __restrict__ bq, const float* __restrict__ bk,
    const float* __restrict__ bv, float* __restrict__ dst)
{
    int t = blockIdx.x * 256 + threadIdx.x;
    if (t >= 4 * 2304) return;
    int e = t / 2304, n = t - e * 2304;
    float v = (n < 768) ? bq[e * 768 + n]
            : (n < 1536) ? bk[e * 768 + n - 768]
            : bv[e * 768 + n - 1536];
    dst[t] = v;
}

// ---------------------------------------------------------------------------
// bf16 GEMM: C[z] = A[z] * B^T (+bias) (gelu?) (+resid)
//   A TILED [mtile64][kw][64][8] per batch; B TILED [ntile128][kw][128][8].
//   Tile 64x128 (MxN), BK=32, 4 waves each 32x64 via 2x4 MFMA 16x16x32.
//   A: DIRECT GLOBAL->REGISTER (no LDS) — per-lane coalesced dwordx4,
//   prefetch distance 2, 3-buffer ring (compile-time indexed via unroll-6).
//   B: 6-slab LDS ring, counted vmcnt(6) (never 0 until tail). LDS=48 KB
//   (B only) -> 3 blocks/CU. Removes 1/3 of LDS traffic vs A-in-LDS.
//   XCD-chunked bijective swizzle keeps panel-sharing blocks on one L2.
//   OUT_MODE: 0 f32 row-major, 1 bf16 row-major, 2 bf16 tiled.
//   RES_MODE: 0 none, 1 f32 row-major, 2 bf16 tiled.
//   Requires M=512, N%128==0, K%192==0 (nK divisible by 6).
// ---------------------------------------------------------------------------
#define SLABB 4096    // 128*32 elems = 8 KB

template<int OUT_MODE, int RES_MODE>
__global__ __launch_bounds__(256) void gemm_bf16_kernel(
    const u16* __restrict__ A, long long sAb,
    const u16* __restrict__ B, const int* __restrict__ bidx, long long sBexp,
    void* __restrict__ Cv, long long sCb, int ldc,
    const float* __restrict__ bias, long long sBiasExp,
    const void* __restrict__ residv, long long sResB, int ldr,
    int act, int N, int K)
{
    // ---- XCD-chunked bijective swizzle (x-fastest linear order) ----
    int nbx = gridDim.x, nby = gridDim.y;
    int nblk = nbx * nby * (int)gridDim.z;
    int lin = blockIdx.x + nbx * (blockIdx.y + nby * blockIdx.z);
    int q = nblk >> 3, r = nblk & 7;
    int xcd = lin & 7, pos = lin >> 3;
    int nl = (xcd < r ? xcd * (q + 1) : r * (q + 1) + (xcd - r) * q) + pos;
    int bx = nl % nbx; int t1 = nl / nbx; int by = t1 % nby; int bz = t1 / nby;

    int zb = bz;
    int kw8 = K >> 3;
    const u16* Ab = A + zb * sAb + (long long)by * kw8 * 512;
    const u16* Bb = B + (bidx ? (long long)bidx[zb] * sBexp : 0)
                      + (long long)bx * kw8 * 1024;
    const float* biasb = bias ? (bias + (bidx ? (long long)bidx[zb] * sBiasExp : 0)) : nullptr;

    __shared__ __align__(16) u16 Bs[6][SLABB];   // 48 KB (B only)

    int tid = threadIdx.x;
    int wave = tid >> 6, lane = tid & 63;
    int wr = wave >> 1, wc = wave & 1;
    int lrow = lane & 15, lkg = lane >> 4;

    f32x4 acc[2][4];
    #pragma unroll
    for (int i = 0; i < 2; i++)
        #pragma unroll
        for (int j = 0; j < 4; j++)
            acc[i][j] = (f32x4){0.f, 0.f, 0.f, 0.f};

    // A per-lane fragment offsets (elems): slab kt is at kt*2048
    long long aoff0 = (long long)lkg * 512 + (wr * 32 + 0 * 16 + lrow) * 8;
    long long aoff1 = (long long)lkg * 512 + (wr * 32 + 1 * 16 + lrow) * 8;

    const u16* bgt = Bb + tid * 8;
    u16* bl0 = (u16*)Bs + tid * 8;
    u16* bl1 = (u16*)Bs + (tid + 256) * 8;

    s16x8 abuf[3][2];   // ring, compile-time indexed

    int nK = K >> 5;   // divisible by 6 (24 or 96)

    // prologue — queue order: B0,B1,B2,A0,B3,A1,B4
    gload16(bgt,            bl0);
    gload16(bgt + 2048,     bl1);
    gload16(bgt + SLABB,        bl0 + SLABB);
    gload16(bgt + SLABB + 2048, bl1 + SLABB);
    gload16(bgt + 2 * SLABB,        bl0 + 2 * SLABB);
    gload16(bgt + 2 * SLABB + 2048, bl1 + 2 * SLABB);
    abuf[0][0] = *(const s16x8*)(Ab + aoff0);
    abuf[0][1] = *(const s16x8*)(Ab + aoff1);
    gload16(bgt + 3 * SLABB,        bl0 + 3 * SLABB);
    gload16(bgt + 3 * SLABB + 2048, bl1 + 3 * SLABB);
    abuf[1][0] = *(const s16x8*)(Ab + 2048 + aoff0);
    abuf[1][1] = *(const s16x8*)(Ab + 2048 + aoff1);
    gload16(bgt + 4 * SLABB,        bl0 + 4 * SLABB);
    gload16(bgt + 4 * SLABB + 2048, bl1 + 4 * SLABB);

    for (int ktb = 0; ktb < nK; ktb += 6) {
        #pragma unroll
        for (int u = 0; u < 6; ++u) {
            int kt = ktb + u;
            if (kt + 6 <= nK) asm volatile("s_waitcnt vmcnt(6)" ::: "memory");
            else              asm volatile("s_waitcnt vmcnt(0)" ::: "memory");
            __builtin_amdgcn_s_barrier();        // slab kt ready; slab kt-1 free
            __builtin_amdgcn_sched_barrier(0);

            // prefetch A(kt+2) -> reg ring (compiler inserts its own wait)
            if (kt + 2 < nK) {
                const u16* ap = Ab + (long long)(kt + 2) * 2048;
                abuf[(u + 2) % 3][0] = *(const s16x8*)(ap + aoff0);
                abuf[(u + 2) % 3][1] = *(const s16x8*)(ap + aoff1);
            }
            // stage B(kt+5) into vacated slab
            if (kt + 5 < nK) {
                const u16* bp = bgt + (long long)(kt + 5) * SLABB;
                int sl = (u + 5) % 6;
                gload16(bp,        bl0 + sl * SLABB);
                gload16(bp + 2048, bl1 + sl * SLABB);
            }

            const u16* Bsb = &Bs[u][0];
            s16x8 bf[4];
            #pragma unroll
            for (int j = 0; j < 4; ++j)
                bf[j] = *(const s16x8*)&Bsb[(lkg * 128 + wc * 64 + j * 16 + lrow) * 8];
            #pragma unroll
            for (int i = 0; i < 2; ++i)
                #pragma unroll
                for (int j = 0; j < 4; ++j)
                    acc[i][j] = __builtin_amdgcn_mfma_f32_16x16x32_bf16(abuf[u % 3][i], bf[j], acc[i][j], 0, 0, 0);
        }
    }

    // epilogue: C/D layout col=lane&15, row=(lane>>4)*4+reg
    int n0 = bx * 128;
    int m0 = by * 64;
    float* Cf = (float*)Cv + zb * sCb;
    u16* Ch = (u16*)Cv + zb * sCb;
    const float* Rf = (const float*)residv + zb * sResB;
    const u16* Rh = (const u16*)residv + zb * sResB;
    int col16 = lane & 15;
    int rq = (lane >> 4) * 4;
    #pragma unroll
    for (int j = 0; j < 4; ++j) {
        int n = n0 + wc * 64 + j * 16 + col16;
        float bv = biasb ? biasb[n] : 0.0f;
        #pragma unroll
        for (int i = 0; i < 2; ++i) {
            #pragma unroll
            for (int r2 = 0; r2 < 4; ++r2) {
                int m = m0 + wr * 32 + i * 16 + rq + r2;
                float v = acc[i][j][r2] + bv;
                if (act == 1) v = gelu_exact(v);
                if (RES_MODE == 1) v += Rf[(long long)m * ldr + n];
                if (RES_MODE == 2) v += bf2f(Rh[tix(m, n, ldr)]);
                if (OUT_MODE == 0) Cf[(long long)m * ldc + n] = v;
                if (OUT_MODE == 1) Ch[(long long)m * ldc + n] = f2bf(v);
                if (OUT_MODE == 2) Ch[tix(m, n, ldc)] = f2bf(v);
            }
        }
    }
}

// ---------------------------------------------------------------------------
// Fused flash attention (bf16): O = softmax(scale * Q K^T [causal]) V.
// QKV bf16 ROW-MAJOR [B][T][3*D]; Out bf16 TILED (A-layout for next GEMM).
// Grid (T/64, B*H), 256 threads = 4 waves, each wave owns 16 query rows.
// ---------------------------------------------------------------------------
__global__ __launch_bounds__(256, 2) void attn_kernel(
    const u16* __restrict__ QKV, u16* __restrict__ Out,
    int causal, float scale)
{
    int qt = blockIdx.x;
    int bh = blockIdx.y;
    int b = bh >> 3;
    int h = bh & 7;
    const u16* Qb = QKV + (long long)b * TT * 3 * DD + (long long)h * HDIM;
    const u16* Kb = Qb + DD;
    const u16* Vb = Qb + 2 * DD;
    u16* Ob = Out + (long long)b * TT * DD;   // tiled within batch

    __shared__ __align__(16) u16 Qs[64 * 104];  // [qrow][d], stride 104
    __shared__ __align__(16) u16 Ks[64 * 104];
    __shared__ __align__(16) u16 Vs[96 * 72];   // [d][krow], stride 72
    __shared__ __align__(16) u16 Ps[64 * 72];   // [qrow][krow]

    int tid = threadIdx.x;
    int wave = tid >> 6;
    int lane = tid & 63;
    int col16 = lane & 15;
    int lkg = lane >> 4;
    int lk = lkg * 8;
    int m0 = qt * 64;

    // ---- stage Q tile 64x96 bf16 ----
    #pragma unroll
    for (int it = 0; it < 3; ++it) {
        int s = tid + it * 256;
        int r = s / 12, c8 = (s % 12) * 8;
        *(s16x8*)&Qs[r * 104 + c8] = *(const s16x8*)(Qb + (long long)(m0 + r) * (3 * DD) + c8);
    }
    __syncthreads();

    s16x8 qf[3];
    #pragma unroll
    for (int kk = 0; kk < 3; ++kk)
        qf[kk] = *(const s16x8*)&Qs[(wave * 16 + col16) * 104 + kk * 32 + lk];

    // ---- QK^T ----
    f32x4 acc[32];
    #pragma unroll
    for (int n = 0; n < 32; ++n) acc[n] = (f32x4){0.f, 0.f, 0.f, 0.f};

    #pragma unroll
    for (int kt = 0; kt < 8; ++kt) {
        #pragma unroll
        for (int it = 0; it < 3; ++it) {
            int s = tid + it * 256;
            int r = s / 12, c8 = (s % 12) * 8;
            *(s16x8*)&Ks[r * 104 + c8] = *(const s16x8*)(Kb + (long long)(kt * 64 + r) * (3 * DD) + c8);
        }
        __syncthreads();
        #pragma unroll
        for (int kk = 0; kk < 3; ++kk) {
            #pragma unroll
            for (int j = 0; j < 4; ++j) {
                s16x8 bfr = *(const s16x8*)&Ks[(j * 16 + col16) * 104 + kk * 32 + lk];
                acc[kt * 4 + j] = __builtin_amdgcn_mfma_f32_16x16x32_bf16(qf[kk], bfr, acc[kt * 4 + j], 0, 0, 0);
            }
        }
        __syncthreads();
    }

    // ---- softmax (registers + shfl only) ----
    int rowbase = m0 + wave * 16 + lkg * 4;
    float mx[4];
    #pragma unroll
    for (int r = 0; r < 4; ++r) mx[r] = -3.0e38f;
    #pragma unroll
    for (int n = 0; n < 32; ++n) {
        int colg = n * 16 + col16;
        #pragma unroll
        for (int r = 0; r < 4; ++r) {
            float v = acc[n][r] * scale;
            if (causal && colg > rowbase + r) v = -3.0e38f;
            acc[n][r] = v;
            mx[r] = fmaxf(mx[r], v);
        }
    }
    #pragma unroll
    for (int m = 1; m <= 8; m <<= 1)
        #pragma unroll
        for (int r = 0; r < 4; ++r)
            mx[r] = fmaxf(mx[r], __shfl_xor(mx[r], m, 64));

    float sum[4] = {0.f, 0.f, 0.f, 0.f};
    #pragma unroll
    for (int n = 0; n < 32; ++n) {
        #pragma unroll
        for (int r = 0; r < 4; ++r) {
            float e = __expf(acc[n][r] - mx[r]);
            acc[n][r] = e;
            sum[r] += e;
        }
    }
    #pragma unroll
    for (int m = 1; m <= 8; m <<= 1)
        #pragma unroll
        for (int r = 0; r < 4; ++r)
            sum[r] += __shfl_xor(sum[r], m, 64);
    float inv[4];
    #pragma unroll
    for (int r = 0; r < 4; ++r) inv[r] = 1.0f / sum[r];

    // ---- PV ----
    f32x4 oacc[6];
    #pragma unroll
    for (int j = 0; j < 6; ++j) oacc[j] = (f32x4){0.f, 0.f, 0.f, 0.f};

    #pragma unroll
    for (int kt = 0; kt < 8; ++kt) {
        __syncthreads();
        #pragma unroll
        for (int j = 0; j < 4; ++j) {
            #pragma unroll
            for (int r = 0; r < 4; ++r)
                Ps[(wave * 16 + lkg * 4 + r) * 72 + j * 16 + col16] = f2bf(acc[kt * 4 + j][r]);
        }
        #pragma unroll
        for (int it = 0; it < 3; ++it) {
            int s = tid + it * 256;
            int key = s / 12, c8 = (s % 12) * 8;
            s16x8 v = *(const s16x8*)(Vb + (long long)(kt * 64 + key) * (3 * DD) + c8);
            #pragma unroll
            for (int e = 0; e < 8; ++e)
                Vs[(c8 + e) * 72 + key] = (u16)v[e];
        }
        __syncthreads();
        #pragma unroll
        for (int kk = 0; kk < 2; ++kk) {
            s16x8 pf = *(const s16x8*)&Ps[(wave * 16 + col16) * 72 + kk * 32 + lk];
            #pragma unroll
            for (int j = 0; j < 6; ++j) {
                s16x8 vf = *(const s16x8*)&Vs[(j * 16 + col16) * 72 + kk * 32 + lk];
                oacc[j] = __builtin_amdgcn_mfma_f32_16x16x32_bf16(pf, vf, oacc[j], 0, 0, 0);
            }
        }
    }

    // ---- epilogue: write TILED ----
    int rquad = lkg * 4;
    #pragma unroll
    for (int j = 0; j < 6; ++j) {
        int d = h * 96 + j * 16 + col16;
        #pragma unroll
        for (int r = 0; r < 4; ++r) {
            int row = m0 + wave * 16 + rquad + r;
            Ob[tix(row, d, DD)] = f2bf(oacc[j][r] * inv[r]);
        }
    }
}

// ---------------------------------------------------------------------------
// LayerNorm over last dim (768), bf16 TILED output. One block per row.
// ---------------------------------------------------------------------------
__global__ __launch_bounds__(256) void ln_kernel(
    const float* __restrict__ x, const float* __restrict__ g,
    const float* __restrict__ b, u16* __restrict__ out)
{
    long long row = blockIdx.x;
    const float* xr = x + row * DD;
    u16* ob = out + (row >> 9) * ((long long)TT * DD);  // batch base
    int m = (int)(row & 511);
    int t = threadIdx.x;
    float vals[3];
    float s = 0.f, ss = 0.f;
    #pragma unroll
    for (int i = 0; i < 3; i++) {
        float v = xr[t + i * 256];
        vals[i] = v; s += v; ss += v * v;
    }
    __shared__ float rs[256], rss[256];
    rs[t] = s; rss[t] = ss; __syncthreads();
    for (int k = 128; k > 0; k >>= 1) {
        if (t < k) { rs[t] += rs[t + k]; rss[t] += rss[t + k]; }
        __syncthreads();
    }
    float mean = rs[0] * (1.0f / DD);
    float var = rss[0] * (1.0f / DD) - mean * mean;
    float inv = rsqrtf(var + 1e-5f);
    #pragma unroll
    for (int i = 0; i < 3; i++) {
        int d = t + i * 256;
        ob[tix(m, d, DD)] = f2bf((vals[i] - mean) * inv * g[d] + b[d]);
    }
}

// ---------------------------------------------------------------------------
// Router part 1: partial column sums of x over T.
// ---------------------------------------------------------------------------
__global__ __launch_bounds__(256) void mean_part_kernel(
    const float* __restrict__ x, float* __restrict__ part)
{
    int b = blockIdx.x, dseg = blockIdx.y, rc = blockIdx.z;
    int d = dseg * 256 + threadIdx.x;
    const float* xb = x + (long long)b * TT * DD;
    float s = 0.f;
    int r0 = rc * 64;
    for (int r = r0; r < r0 + 64; ++r) s += xb[(long long)r * DD + d];
    part[((long long)b * 8 + rc) * DD + d] = s;
}

// ---------------------------------------------------------------------------
// Router part 2.
// ---------------------------------------------------------------------------
__global__ __launch_bounds__(128) void router_kernel(
    const float* __restrict__ part, const float* __restrict__ w1,
    const float* __restrict__ b1, const float* __restrict__ w2,
    const float* __restrict__ b2, int* __restrict__ idx)
{
    int b = blockIdx.x, t = threadIdx.x;
    __shared__ float xm[DD];
    __shared__ float h[128];
    __shared__ float logits[8];
    for (int i = t; i < DD; i += 128) {
        float s = 0.f;
        for (int rc = 0; rc < 8; ++rc) s += part[((long long)b * 8 + rc) * DD + i];
        xm[i] = s * (1.0f / TT);
    }
    __syncthreads();
    {
        float s = b1[t];
        const float* w = w1 + (long long)t * DD;
        for (int d = 0; d < DD; ++d) s += xm[d] * w[d];
        h[t] = gelu_exact(s);
    }
    __syncthreads();
    if (t < 8) {
        float s = b2[t];
        const float* w = w2 + t * 128;
        for (int d = 0; d < 128; ++d) s += h[d] * w[d];
        logits[t] = s;
    }
    __syncthreads();
    if (t == 0) {
        int bsix = 0;
        for (int i = 1; i < 4; i++) if (logits[i] > logits[bsix]) bsix = i;
        int btix = 4;
        for (int i = 5; i < 8; i++) if (logits[i] > logits[btix]) btix = i;
        idx[b] = bsix;
        idx[b + BB] = btix - 4;
    }
}

// ---------------------------------------------------------------------------
static void run_gemm2(hipStream_t stream,
    const u16* A, long long sAb,
    const u16* B, const int* bidx, long long sBexp,
    void* C, long long sCb, int ldc,
    const float* bias, long long sBiasExp,
    const void* resid, long long sResB, int ldr,
    int act, int N, int K, int outmode, int resmode)
{
    dim3 grid(N / 128, 8, BB);
    if (outmode == 1)
        gemm_bf16_kernel<1, 0><<<grid, 256, 0, stream>>>(A, sAb, B, bidx, sBexp,
            C, sCb, ldc, bias, sBiasExp, resid, sResB, ldr, act, N, K);
    else if (outmode == 2 && resmode == 0)
        gemm_bf16_kernel<2, 0><<<grid, 256, 0, stream>>>(A, sAb, B, bidx, sBexp,
            C, sCb, ldc, bias, sBiasExp, resid, sResB, ldr, act, N, K);
    else if (outmode == 2)
        gemm_bf16_kernel<2, 2><<<grid, 256, 0, stream>>>(A, sAb, B, bidx, sBexp,
            C, sCb, ldc, bias, sBiasExp, resid, sResB, ldr, act, N, K);
    else
        gemm_bf16_kernel<0, 1><<<grid, 256, 0, stream>>>(A, sAb, B, bidx, sBexp,
            C, sCb, ldc, bias, sBiasExp, resid, sResB, ldr, act, N, K);
}

extern "C" void kernel_launch(void* const* d_in, const int* in_sizes, int n_in,
                              void* d_out, int out_size, void* d_ws, size_t ws_size,
                              hipStream_t stream)
{
    const float* x       = (const float*)d_in[0];
    const float* rw1     = (const float*)d_in[1];
    const float* rb1     = (const float*)d_in[2];
    const float* rw2     = (const float*)d_in[3];
    const float* rb2     = (const float*)d_in[4];
    const float* gs      = (const float*)d_in[5];
    const float* bs      = (const float*)d_in[6];
    const float* gt      = (const float*)d_in[7];
    const float* btt     = (const float*)d_in[8];
    const float* gm      = (const float*)d_in[9];
    const float* bm      = (const float*)d_in[10];
    const float* sp_wqkv = (const float*)d_in[11];
    const float* sp_bqkv = (const float*)d_in[12];
    const float* sp_wo   = (const float*)d_in[13];
    const float* sp_bo   = (const float*)d_in[14];
    const float* tp_wq   = (const float*)d_in[15];
    const float* tp_bq   = (const float*)d_in[16];
    const float* tp_wk   = (const float*)d_in[17];
    const float* tp_bk   = (const float*)d_in[18];
    const float* tp_wv   = (const float*)d_in[19];
    const float* tp_bv   = (const float*)d_in[20];
    const float* tp_wo   = (const float*)d_in[21];
    const float* tp_bo   = (const float*)d_in[22];
    const float* c_wqkv  = (const float*)d_in[23];
    const float* c_bqkv  = (const float*)d_in[24];
    const float* c_wo    = (const float*)d_in[25];
    const float* c_bo    = (const float*)d_in[26];
    const float* m_w1    = (const float*)d_in[27];
    const float* m_b1    = (const float*)d_in[28];
    const float* m_w2    = (const float*)d_in[29];
    const float* m_b2    = (const float*)d_in[30];
    float* out = (float*)d_out;

    float* ws = (float*)d_ws;
    size_t o = 0;
    float* part  = ws + o; o += (size_t)BB * 8 * DD;
    int*   idx   = (int*)(ws + o); o += 16;
    float* tpb   = ws + o; o += 4 * 2304;                     // packed temporal bias
    float* x1b   = ws + o; o += (size_t)4096 * DD;            // f32 (x + fused)
    u16* xnb   = (u16*)(ws + o); o += (size_t)4096 * DD / 2;  // LN out (tiled bf16)
    u16* tmp1b = (u16*)(ws + o); o += (size_t)4096 * DD / 2;  // attn out (tiled)
    u16* tmp2b = (u16*)(ws + o); o += (size_t)4096 * DD / 2;  // LN for mlp (tiled)
    u16* soutb = (u16*)(ws + o); o += (size_t)4096 * DD / 2;  // spatial_out (tiled)
    u16* toutb = (u16*)(ws + o); o += (size_t)4096 * DD / 2;  // temporal_out (tiled)
    u16* qkvb  = (u16*)(ws + o); o += (size_t)4096 * 2304 / 2;// q|k|v row-major bf16
    u16* yb    = (u16*)(ws + o); o += (size_t)4096 * 3072 / 2;// mlp hidden (tiled)
    u16* wpool = (u16*)(ws + o); o += (size_t)CUM10 / 2;      // bf16 weights (tiled)

    u16* w_sp_qkv = wpool;
    u16* w_sp_wo  = wpool + CUM1;
    u16* w_tp_qkv = wpool + CUM2;   // interleaved [e][2304][768] tiled
    u16* w_tp_o   = wpool + CUM5;
    u16* w_c_qkv  = wpool + CUM6;
    u16* w_c_wo   = wpool + CUM7;
    u16* w_m1     = wpool + CUM8;
    u16* w_m2     = wpool + CUM9;

    int* idx_s = idx;
    int* idx_t = idx + BB;

    const long long sTD  = (long long)TT * DD;       // 512*768
    const long long sT3D = (long long)TT * 3 * DD;   // 512*2304
    const long long sT4D = (long long)TT * 4 * DD;   // 512*3072
    const float qk_scale = 1.0f / sqrtf((float)HDIM);

    // ---- weight convert (f32 -> bf16 tiled) + temporal bias pack ----
    cvt_kernel<<<(int)((CUM10 / 8 + 255) / 256), 256, 0, stream>>>(
        sp_wqkv, sp_wo, tp_wq, tp_wk, tp_wv, tp_wo, c_wqkv, c_wo, m_w1, m_w2, wpool);
    pack_tpb_kernel<<<36, 256, 0, stream>>>(tp_bq, tp_bk, tp_bv, tpb);

    // ---- router ----
    mean_part_kernel<<<dim3(BB, 3, 8), 256, 0, stream>>>(x, part);
    router_kernel<<<BB, 128, 0, stream>>>(part, rw1, rb1, rw2, rb2, idx);

    // ---- spatial branch ----
    ln_kernel<<<4096, 256, 0, stream>>>(x, gs, bs, xnb);
    // qkv = xn @ sp_wqkv[idx_s]^T + sp_bqkv[idx_s]  -> row-major for attn
    run_gemm2(stream, xnb, sTD, w_sp_qkv, idx_s, 3 * DDDD,
              qkvb, sT3D, 3 * DD, sp_bqkv, 3 * DD, nullptr, 0, 0,
              0, 3 * DD, DD, 1, 0);
    attn_kernel<<<dim3(TT / 64, BB * HH), 256, 0, stream>>>(qkvb, tmp1b, 0, qk_scale);
    // spatial_out = O @ sp_wo[idx_s]^T + sp_bo[idx_s]  -> tiled
    run_gemm2(stream, tmp1b, sTD, w_sp_wo, idx_s, DDDD,
              soutb, sTD, DD, sp_bo, DD, nullptr, 0, 0,
              0, DD, DD, 2, 0);

    // ---- temporal branch ----
    ln_kernel<<<4096, 256, 0, stream>>>(x, gt, btt, xnb);
    run_gemm2(stream, xnb, sTD, w_tp_qkv, idx_t, 3 * DDDD,
              qkvb, sT3D, 3 * DD, tpb, 3 * DD, nullptr, 0, 0,
              0, 3 * DD, DD, 1, 0);
    attn_kernel<<<dim3(TT / 64, BB * HH), 256, 0, stream>>>(qkvb, tmp1b, 1, qk_scale);
    // temporal_out = xt + O @ tp_wo[idx_t]^T + tp_bo[idx_t]  (tiled, tiled resid)
    run_gemm2(stream, tmp1b, sTD, w_tp_o, idx_t, DDDD,
              toutb, sTD, DD, tp_bo, DD, xnb, sTD, DD,
              0, DD, DD, 2, 2);

    // ---- cross attention ----
    run_gemm2(stream, soutb, sTD, w_c_qkv, nullptr, 0,
              qkvb, sT3D, 3 * DD, c_bqkv, 0, nullptr, 0, 0,
              0, DD, DD, 1, 0);
    // rows 768..2303 of c_wqkv = tiles 6.. -> offset DDDD elems
    run_gemm2(stream, toutb, sTD, w_c_qkv + DDDD, nullptr, 0,
              qkvb + DD, sT3D, 3 * DD, c_bqkv + DD, 0, nullptr, 0, 0,
              0, 2 * DD, DD, 1, 0);
    attn_kernel<<<dim3(TT / 64, BB * HH), 256, 0, stream>>>(qkvb, tmp1b, 0, qk_scale);
    // x1 = x + (fused_attn @ cross_wo^T + cross_bo)   (f32 out, f32 resid)
    run_gemm2(stream, tmp1b, sTD, w_c_wo, nullptr, 0,
              x1b, sTD, DD, c_bo, 0, x, sTD, DD,
              0, DD, DD, 0, 1);

    // ---- MLP ----
    ln_kernel<<<4096, 256, 0, stream>>>(x1b, gm, bm, tmp2b);
    // y = gelu(ln @ mlp_w1^T + b1) -> tiled bf16
    run_gemm2(stream, tmp2b, sTD, w_m1, nullptr, 0,
              yb, sT4D, 4 * DD, m_b1, 0, nullptr, 0, 0,
              1, 4 * DD, DD, 2, 0);
    // out = x1 + y @ mlp_w2^T + b2   (f32 out, f32 resid)
    run_gemm2(stream, yb, sT4D, w_m2, nullptr, 0,
              out, sTD, DD, m_b2, 0, x1b, sTD, DD,
              0, DD, 4 * DD, 0, 1);
}

// Round 9
// 613.340 us; speedup vs baseline: 1.2041x; 1.0190x over previous
//
#include <hip/hip_runtime.h>
#include <math.h>

// Problem constants
#define BB 8
#define TT 512
#define DD 768
#define HH 8
#define HDIM 96
#define DDDD 589824LL   // 768*768

typedef short s16x8 __attribute__((ext_vector_type(8)));
typedef float f32x4 __attribute__((ext_vector_type(4)));
typedef unsigned short u16;

__device__ inline unsigned short f2bf(float f) {
    union { float f; unsigned u; } v; v.f = f;
    unsigned u = v.u;
    unsigned r = (u + 0x7fffu + ((u >> 16) & 1u)) >> 16;
    return (unsigned short)r;
}

__device__ inline float bf2f(u16 h) {
    union { unsigned u; float f; } v; v.u = ((unsigned)h) << 16; return v.f;
}

__device__ inline float gelu_exact(float x) {
    return 0.5f * x * (1.0f + erff(x * 0.70710678118654752440f));
}

__device__ __forceinline__ void gload16(const void* g, void* l) {
    __builtin_amdgcn_global_load_lds(
        (const __attribute__((address_space(1))) unsigned int*)g,
        (__attribute__((address_space(3))) unsigned int*)l,
        16, 0, 0);
}

// Tiled activation index: 64-row tiles, k-major windows of 8.
// elem (m, k) of a [M][ldn] matrix -> ((m/64)*(ldn/8) + k/8)*512 + (m%64)*8 + k%8
__device__ __forceinline__ long long tix(int m, int k, int ldn) {
    return ((long long)(m >> 6) * (ldn >> 3) + (k >> 3)) * 512 + ((m & 63) << 3) + (k & 7);
}

// ---------------------------------------------------------------------------
// Weight convert: f32 -> bf16 into k-major TILED layout
//   B'[ntile128][kw=K/8][row128][8] (experts consecutive).
// LDS-staged block transpose: one block per 128n x 64k tile.
//   read : 8-float runs per thread (rows 256B-contiguous), cvt -> LDS
//   write: 16 KB tile dumped CONTIGUOUSLY (thread sl -> dst + sl*16B)
// tp_wq/wk/wv interleave handled by n->source remap in the read phase.
// ---------------------------------------------------------------------------
#define CUM1  7077888LL
#define CUM2  9437184LL
#define CUM5  16515072LL
#define CUM6  18874368LL
#define CUM7  20643840LL
#define CUM8  21233664LL
#define CUM9  23592960LL
#define CUM10 25952256LL

// region tile counts (8192 out-elems per tile):
//   R0 sp_wqkv 864 | R1 sp_wo 288 | R2 tp_qkv 864 | R3 tp_wo 288
//   R4 c_wqkv 216 | R5 c_wo 72 | R6 m_w1 288 | R7 m_w2 288   -> 3168 total
__global__ __launch_bounds__(256) void cvt_kernel(
    const float* __restrict__ s0, const float* __restrict__ s1,
    const float* __restrict__ s2, const float* __restrict__ s3,
    const float* __restrict__ s4, const float* __restrict__ s5,
    const float* __restrict__ s6, const float* __restrict__ s7,
    const float* __restrict__ s8, const float* __restrict__ s9,
    u16* __restrict__ dpool)
{
    int t = blockIdx.x;
    const float* sa = nullptr; const float* sb = nullptr; const float* sc = nullptr;
    long long dbase; int K = 768; int tpmode = 0;
    if (t < 864) {                       // sp_wqkv: 4 x [2304][768]
        int e = t / 216; t -= e * 216;
        sa = s0 + (long long)e * 2304 * 768; dbase = e * 3 * DDDD;
    } else if (t < 1152) {               // sp_wo: 4 x [768][768]
        t -= 864; int e = t / 72; t -= e * 72;
        sa = s1 + (long long)e * DDDD; dbase = CUM1 + e * DDDD;
    } else if (t < 2016) {               // tp_wq|wk|wv interleaved [2304][768]
        t -= 1152; int e = t / 216; t -= e * 216; tpmode = 1;
        sa = s2 + (long long)e * DDDD; sb = s3 + (long long)e * DDDD;
        sc = s4 + (long long)e * DDDD; dbase = CUM2 + e * 3 * DDDD;
    } else if (t < 2304) {               // tp_wo: 4 x [768][768]
        t -= 2016; int e = t / 72; t -= e * 72;
        sa = s5 + (long long)e * DDDD; dbase = CUM5 + e * DDDD;
    } else if (t < 2520) {               // c_wqkv: [2304][768]
        t -= 2304; sa = s6; dbase = CUM6;
    } else if (t < 2592) {               // c_wo: [768][768]
        t -= 2520; sa = s7; dbase = CUM7;
    } else if (t < 2880) {               // m_w1: [3072][768]
        t -= 2592; sa = s8; dbase = CUM8;
    } else {                             // m_w2: [768][3072]
        t -= 2880; sa = s9; dbase = CUM9; K = 3072;
    }
    int tiles_k = K >> 6;
    int nt = t / tiles_k, kb = t - nt * tiles_k;
    int n0 = nt * 128, k0 = kb * 64;

    __shared__ u16 lds[8256];   // (kw*129 + r)*8, kw<8, r<128

    int tid = threadIdx.x;
    #pragma unroll
    for (int it = 0; it < 4; ++it) {
        int sl = tid + it * 256;
        int r = sl >> 3, kw = sl & 7;
        int n = n0 + r;
        const float* src;
        if (tpmode) {
            if (n < 768)       src = sa + (long long)n * 768;
            else if (n < 1536) src = sb + (long long)(n - 768) * 768;
            else               src = sc + (long long)(n - 1536) * 768;
            src += k0 + kw * 8;
        } else {
            src = sa + (long long)n * K + k0 + kw * 8;
        }
        float4 a = *(const float4*)src;
        float4 b = *(const float4*)(src + 4);
        s16x8 o;
        o[0] = f2bf(a.x); o[1] = f2bf(a.y); o[2] = f2bf(a.z); o[3] = f2bf(a.w);
        o[4] = f2bf(b.x); o[5] = f2bf(b.y); o[6] = f2bf(b.z); o[7] = f2bf(b.w);
        *(s16x8*)&lds[(kw * 129 + r) * 8] = o;
    }
    __syncthreads();
    long long dbase2 = dbase + ((long long)nt * (K >> 3) + (long long)kb * 8) * 1024;
    #pragma unroll
    for (int it = 0; it < 4; ++it) {
        int sl = tid + it * 256;
        int kw = sl >> 7, r = sl & 127;
        *(s16x8*)(dpool + dbase2 + (long long)sl * 8) = *(const s16x8*)&lds[(kw * 129 + r) * 8];
    }
}

// pack temporal biases [4][2304] = bq|bk|bv
__global__ __launch_bounds__(256) void pack_tpb_kernel(
    const float* __restrict__ bq, const float* __restrict__ bk,
    const float* __restrict__ bv, float* __restrict__ dst)
{
    int t = blockIdx.x * 256 + threadIdx.x;
    if (t >= 4 * 2304) return;
    int e = t / 2304, n = t - e * 2304;
    float v = (n < 768) ? bq[e * 768 + n]
            : (n < 1536) ? bk[e * 768 + n - 768]
            : bv[e * 768 + n - 1536];
    dst[t] = v;
}

// ---------------------------------------------------------------------------
// bf16 GEMM: C[z] = A[z] * B^T (+bias) (gelu?) (+resid)
//   A TILED [mtile64][kw][64][8] per batch; B TILED [ntile128][kw][128][8].
//   Tile 64x128 (MxN), BK=32, 4 waves each 32x64 via 2x4 MFMA 16x16x32.
//   A: DIRECT GLOBAL->REGISTER (no LDS), prefetch distance 2, 3-buf ring.
//   B: 6-slab LDS ring, counted vmcnt(6). LDS=48 KB -> 3 blocks/CU.
//   XCD-chunked bijective swizzle for L2 locality.
//   OUT_MODE: 0 f32 row-major, 1 bf16 row-major, 2 bf16 tiled.
//   RES_MODE: 0 none, 1 f32 row-major, 2 bf16 tiled.
//   Requires M=512, N%128==0, K%192==0 (nK divisible by 6).
// ---------------------------------------------------------------------------
#define SLABB 4096    // 128*32 elems = 8 KB

template<int OUT_MODE, int RES_MODE>
__global__ __launch_bounds__(256) void gemm_bf16_kernel(
    const u16* __restrict__ A, long long sAb,
    const u16* __restrict__ B, const int* __restrict__ bidx, long long sBexp,
    void* __restrict__ Cv, long long sCb, int ldc,
    const float* __restrict__ bias, long long sBiasExp,
    const void* __restrict__ residv, long long sResB, int ldr,
    int act, int N, int K)
{
    // ---- XCD-chunked bijective swizzle (x-fastest linear order) ----
    int nbx = gridDim.x, nby = gridDim.y;
    int nblk = nbx * nby * (int)gridDim.z;
    int lin = blockIdx.x + nbx * (blockIdx.y + nby * blockIdx.z);
    int q = nblk >> 3, r = nblk & 7;
    int xcd = lin & 7, pos = lin >> 3;
    int nl = (xcd < r ? xcd * (q + 1) : r * (q + 1) + (xcd - r) * q) + pos;
    int bx = nl % nbx; int t1 = nl / nbx; int by = t1 % nby; int bz = t1 / nby;

    int zb = bz;
    int kw8 = K >> 3;
    const u16* Ab = A + zb * sAb + (long long)by * kw8 * 512;
    const u16* Bb = B + (bidx ? (long long)bidx[zb] * sBexp : 0)
                      + (long long)bx * kw8 * 1024;
    const float* biasb = bias ? (bias + (bidx ? (long long)bidx[zb] * sBiasExp : 0)) : nullptr;

    __shared__ __align__(16) u16 Bs[6][SLABB];   // 48 KB (B only)

    int tid = threadIdx.x;
    int wave = tid >> 6, lane = tid & 63;
    int wr = wave >> 1, wc = wave & 1;
    int lrow = lane & 15, lkg = lane >> 4;

    f32x4 acc[2][4];
    #pragma unroll
    for (int i = 0; i < 2; i++)
        #pragma unroll
        for (int j = 0; j < 4; j++)
            acc[i][j] = (f32x4){0.f, 0.f, 0.f, 0.f};

    // A per-lane fragment offsets (elems): slab kt is at kt*2048
    long long aoff0 = (long long)lkg * 512 + (wr * 32 + 0 * 16 + lrow) * 8;
    long long aoff1 = (long long)lkg * 512 + (wr * 32 + 1 * 16 + lrow) * 8;

    const u16* bgt = Bb + tid * 8;
    u16* bl0 = (u16*)Bs + tid * 8;
    u16* bl1 = (u16*)Bs + (tid + 256) * 8;

    s16x8 abuf[3][2];   // ring, compile-time indexed

    int nK = K >> 5;   // divisible by 6 (24 or 96)

    // prologue — queue order: B0,B1,B2,A0,B3,A1,B4
    gload16(bgt,            bl0);
    gload16(bgt + 2048,     bl1);
    gload16(bgt + SLABB,        bl0 + SLABB);
    gload16(bgt + SLABB + 2048, bl1 + SLABB);
    gload16(bgt + 2 * SLABB,        bl0 + 2 * SLABB);
    gload16(bgt + 2 * SLABB + 2048, bl1 + 2 * SLABB);
    abuf[0][0] = *(const s16x8*)(Ab + aoff0);
    abuf[0][1] = *(const s16x8*)(Ab + aoff1);
    gload16(bgt + 3 * SLABB,        bl0 + 3 * SLABB);
    gload16(bgt + 3 * SLABB + 2048, bl1 + 3 * SLABB);
    abuf[1][0] = *(const s16x8*)(Ab + 2048 + aoff0);
    abuf[1][1] = *(const s16x8*)(Ab + 2048 + aoff1);
    gload16(bgt + 4 * SLABB,        bl0 + 4 * SLABB);
    gload16(bgt + 4 * SLABB + 2048, bl1 + 4 * SLABB);

    for (int ktb = 0; ktb < nK; ktb += 6) {
        #pragma unroll
        for (int u = 0; u < 6; ++u) {
            int kt = ktb + u;
            if (kt + 6 <= nK) asm volatile("s_waitcnt vmcnt(6)" ::: "memory");
            else              asm volatile("s_waitcnt vmcnt(0)" ::: "memory");
            __builtin_amdgcn_s_barrier();        // slab kt ready; slab kt-1 free
            __builtin_amdgcn_sched_barrier(0);

            // prefetch A(kt+2) -> reg ring (compiler inserts its own wait)
            if (kt + 2 < nK) {
                const u16* ap = Ab + (long long)(kt + 2) * 2048;
                abuf[(u + 2) % 3][0] = *(const s16x8*)(ap + aoff0);
                abuf[(u + 2) % 3][1] = *(const s16x8*)(ap + aoff1);
            }
            // stage B(kt+5) into vacated slab
            if (kt + 5 < nK) {
                const u16* bp = bgt + (long long)(kt + 5) * SLABB;
                int sl = (u + 5) % 6;
                gload16(bp,        bl0 + sl * SLABB);
                gload16(bp + 2048, bl1 + sl * SLABB);
            }

            const u16* Bsb = &Bs[u][0];
            s16x8 bf[4];
            #pragma unroll
            for (int j = 0; j < 4; ++j)
                bf[j] = *(const s16x8*)&Bsb[(lkg * 128 + wc * 64 + j * 16 + lrow) * 8];
            #pragma unroll
            for (int i = 0; i < 2; ++i)
                #pragma unroll
                for (int j = 0; j < 4; ++j)
                    acc[i][j] = __builtin_amdgcn_mfma_f32_16x16x32_bf16(abuf[u % 3][i], bf[j], acc[i][j], 0, 0, 0);
        }
    }

    // epilogue: C/D layout col=lane&15, row=(lane>>4)*4+reg
    int n0 = bx * 128;
    int m0 = by * 64;
    float* Cf = (float*)Cv + zb * sCb;
    u16* Ch = (u16*)Cv + zb * sCb;
    const float* Rf = (const float*)residv + zb * sResB;
    const u16* Rh = (const u16*)residv + zb * sResB;
    int col16 = lane & 15;
    int rq = (lane >> 4) * 4;
    #pragma unroll
    for (int j = 0; j < 4; ++j) {
        int n = n0 + wc * 64 + j * 16 + col16;
        float bv = biasb ? biasb[n] : 0.0f;
        #pragma unroll
        for (int i = 0; i < 2; ++i) {
            #pragma unroll
            for (int r2 = 0; r2 < 4; ++r2) {
                int m = m0 + wr * 32 + i * 16 + rq + r2;
                float v = acc[i][j][r2] + bv;
                if (act == 1) v = gelu_exact(v);
                if (RES_MODE == 1) v += Rf[(long long)m * ldr + n];
                if (RES_MODE == 2) v += bf2f(Rh[tix(m, n, ldr)]);
                if (OUT_MODE == 0) Cf[(long long)m * ldc + n] = v;
                if (OUT_MODE == 1) Ch[(long long)m * ldc + n] = f2bf(v);
                if (OUT_MODE == 2) Ch[tix(m, n, ldc)] = f2bf(v);
            }
        }
    }
}

// ---------------------------------------------------------------------------
// Fused flash attention (bf16): O = softmax(scale * Q K^T [causal]) V.
// QKV bf16 ROW-MAJOR [B][T][3*D]; Out bf16 TILED (A-layout for next GEMM).
// Grid (T/64, B*H), 256 threads = 4 waves, each wave owns 16 query rows.
// ---------------------------------------------------------------------------
__global__ __launch_bounds__(256, 2) void attn_kernel(
    const u16* __restrict__ QKV, u16* __restrict__ Out,
    int causal, float scale)
{
    int qt = blockIdx.x;
    int bh = blockIdx.y;
    int b = bh >> 3;
    int h = bh & 7;
    const u16* Qb = QKV + (long long)b * TT * 3 * DD + (long long)h * HDIM;
    const u16* Kb = Qb + DD;
    const u16* Vb = Qb + 2 * DD;
    u16* Ob = Out + (long long)b * TT * DD;   // tiled within batch

    __shared__ __align__(16) u16 Qs[64 * 104];  // [qrow][d], stride 104
    __shared__ __align__(16) u16 Ks[64 * 104];
    __shared__ __align__(16) u16 Vs[96 * 72];   // [d][krow], stride 72
    __shared__ __align__(16) u16 Ps[64 * 72];   // [qrow][krow]

    int tid = threadIdx.x;
    int wave = tid >> 6;
    int lane = tid & 63;
    int col16 = lane & 15;
    int lkg = lane >> 4;
    int lk = lkg * 8;
    int m0 = qt * 64;

    // ---- stage Q tile 64x96 bf16 ----
    #pragma unroll
    for (int it = 0; it < 3; ++it) {
        int s = tid + it * 256;
        int r = s / 12, c8 = (s % 12) * 8;
        *(s16x8*)&Qs[r * 104 + c8] = *(const s16x8*)(Qb + (long long)(m0 + r) * (3 * DD) + c8);
    }
    __syncthreads();

    s16x8 qf[3];
    #pragma unroll
    for (int kk = 0; kk < 3; ++kk)
        qf[kk] = *(const s16x8*)&Qs[(wave * 16 + col16) * 104 + kk * 32 + lk];

    // ---- QK^T ----
    f32x4 acc[32];
    #pragma unroll
    for (int n = 0; n < 32; ++n) acc[n] = (f32x4){0.f, 0.f, 0.f, 0.f};

    #pragma unroll
    for (int kt = 0; kt < 8; ++kt) {
        #pragma unroll
        for (int it = 0; it < 3; ++it) {
            int s = tid + it * 256;
            int r = s / 12, c8 = (s % 12) * 8;
            *(s16x8*)&Ks[r * 104 + c8] = *(const s16x8*)(Kb + (long long)(kt * 64 + r) * (3 * DD) + c8);
        }
        __syncthreads();
        #pragma unroll
        for (int kk = 0; kk < 3; ++kk) {
            #pragma unroll
            for (int j = 0; j < 4; ++j) {
                s16x8 bfr = *(const s16x8*)&Ks[(j * 16 + col16) * 104 + kk * 32 + lk];
                acc[kt * 4 + j] = __builtin_amdgcn_mfma_f32_16x16x32_bf16(qf[kk], bfr, acc[kt * 4 + j], 0, 0, 0);
            }
        }
        __syncthreads();
    }

    // ---- softmax (registers + shfl only) ----
    int rowbase = m0 + wave * 16 + lkg * 4;
    float mx[4];
    #pragma unroll
    for (int r = 0; r < 4; ++r) mx[r] = -3.0e38f;
    #pragma unroll
    for (int n = 0; n < 32; ++n) {
        int colg = n * 16 + col16;
        #pragma unroll
        for (int r = 0; r < 4; ++r) {
            float v = acc[n][r] * scale;
            if (causal && colg > rowbase + r) v = -3.0e38f;
            acc[n][r] = v;
            mx[r] = fmaxf(mx[r], v);
        }
    }
    #pragma unroll
    for (int m = 1; m <= 8; m <<= 1)
        #pragma unroll
        for (int r = 0; r < 4; ++r)
            mx[r] = fmaxf(mx[r], __shfl_xor(mx[r], m, 64));

    float sum[4] = {0.f, 0.f, 0.f, 0.f};
    #pragma unroll
    for (int n = 0; n < 32; ++n) {
        #pragma unroll
        for (int r = 0; r < 4; ++r) {
            float e = __expf(acc[n][r] - mx[r]);
            acc[n][r] = e;
            sum[r] += e;
        }
    }
    #pragma unroll
    for (int m = 1; m <= 8; m <<= 1)
        #pragma unroll
        for (int r = 0; r < 4; ++r)
            sum[r] += __shfl_xor(sum[r], m, 64);
    float inv[4];
    #pragma unroll
    for (int r = 0; r < 4; ++r) inv[r] = 1.0f / sum[r];

    // ---- PV ----
    f32x4 oacc[6];
    #pragma unroll
    for (int j = 0; j < 6; ++j) oacc[j] = (f32x4){0.f, 0.f, 0.f, 0.f};

    #pragma unroll
    for (int kt = 0; kt < 8; ++kt) {
        __syncthreads();
        #pragma unroll
        for (int j = 0; j < 4; ++j) {
            #pragma unroll
            for (int r = 0; r < 4; ++r)
                Ps[(wave * 16 + lkg * 4 + r) * 72 + j * 16 + col16] = f2bf(acc[kt * 4 + j][r]);
        }
        #pragma unroll
        for (int it = 0; it < 3; ++it) {
            int s = tid + it * 256;
            int key = s / 12, c8 = (s % 12) * 8;
            s16x8 v = *(const s16x8*)(Vb + (long long)(kt * 64 + key) * (3 * DD) + c8);
            #pragma unroll
            for (int e = 0; e < 8; ++e)
                Vs[(c8 + e) * 72 + key] = (u16)v[e];
        }
        __syncthreads();
        #pragma unroll
        for (int kk = 0; kk < 2; ++kk) {
            s16x8 pf = *(const s16x8*)&Ps[(wave * 16 + col16) * 72 + kk * 32 + lk];
            #pragma unroll
            for (int j = 0; j < 6; ++j) {
                s16x8 vf = *(const s16x8*)&Vs[(j * 16 + col16) * 72 + kk * 32 + lk];
                oacc[j] = __builtin_amdgcn_mfma_f32_16x16x32_bf16(pf, vf, oacc[j], 0, 0, 0);
            }
        }
    }

    // ---- epilogue: write TILED ----
    int rquad = lkg * 4;
    #pragma unroll
    for (int j = 0; j < 6; ++j) {
        int d = h * 96 + j * 16 + col16;
        #pragma unroll
        for (int r = 0; r < 4; ++r) {
            int row = m0 + wave * 16 + rquad + r;
            Ob[tix(row, d, DD)] = f2bf(oacc[j][r] * inv[r]);
        }
    }
}

// ---------------------------------------------------------------------------
// LayerNorm over last dim (768), bf16 TILED output. One block per row.
// ---------------------------------------------------------------------------
__global__ __launch_bounds__(256) void ln_kernel(
    const float* __restrict__ x, const float* __restrict__ g,
    const float* __restrict__ b, u16* __restrict__ out)
{
    long long row = blockIdx.x;
    const float* xr = x + row * DD;
    u16* ob = out + (row >> 9) * ((long long)TT * DD);  // batch base
    int m = (int)(row & 511);
    int t = threadIdx.x;
    float vals[3];
    float s = 0.f, ss = 0.f;
    #pragma unroll
    for (int i = 0; i < 3; i++) {
        float v = xr[t + i * 256];
        vals[i] = v; s += v; ss += v * v;
    }
    __shared__ float rs[256], rss[256];
    rs[t] = s; rss[t] = ss; __syncthreads();
    for (int k = 128; k > 0; k >>= 1) {
        if (t < k) { rs[t] += rs[t + k]; rss[t] += rss[t + k]; }
        __syncthreads();
    }
    float mean = rs[0] * (1.0f / DD);
    float var = rss[0] * (1.0f / DD) - mean * mean;
    float inv = rsqrtf(var + 1e-5f);
    #pragma unroll
    for (int i = 0; i < 3; i++) {
        int d = t + i * 256;
        ob[tix(m, d, DD)] = f2bf((vals[i] - mean) * inv * g[d] + b[d]);
    }
}

// ---------------------------------------------------------------------------
// Router part 1: partial column sums of x over T.
// ---------------------------------------------------------------------------
__global__ __launch_bounds__(256) void mean_part_kernel(
    const float* __restrict__ x, float* __restrict__ part)
{
    int b = blockIdx.x, dseg = blockIdx.y, rc = blockIdx.z;
    int d = dseg * 256 + threadIdx.x;
    const float* xb = x + (long long)b * TT * DD;
    float s = 0.f;
    int r0 = rc * 64;
    for (int r = r0; r < r0 + 64; ++r) s += xb[(long long)r * DD + d];
    part[((long long)b * 8 + rc) * DD + d] = s;
}

// ---------------------------------------------------------------------------
// Router part 2.
// ---------------------------------------------------------------------------
__global__ __launch_bounds__(128) void router_kernel(
    const float* __restrict__ part, const float* __restrict__ w1,
    const float* __restrict__ b1, const float* __restrict__ w2,
    const float* __restrict__ b2, int* __restrict__ idx)
{
    int b = blockIdx.x, t = threadIdx.x;
    __shared__ float xm[DD];
    __shared__ float h[128];
    __shared__ float logits[8];
    for (int i = t; i < DD; i += 128) {
        float s = 0.f;
        for (int rc = 0; rc < 8; ++rc) s += part[((long long)b * 8 + rc) * DD + i];
        xm[i] = s * (1.0f / TT);
    }
    __syncthreads();
    {
        float s = b1[t];
        const float* w = w1 + (long long)t * DD;
        for (int d = 0; d < DD; ++d) s += xm[d] * w[d];
        h[t] = gelu_exact(s);
    }
    __syncthreads();
    if (t < 8) {
        float s = b2[t];
        const float* w = w2 + t * 128;
        for (int d = 0; d < 128; ++d) s += h[d] * w[d];
        logits[t] = s;
    }
    __syncthreads();
    if (t == 0) {
        int bsix = 0;
        for (int i = 1; i < 4; i++) if (logits[i] > logits[bsix]) bsix = i;
        int btix = 4;
        for (int i = 5; i < 8; i++) if (logits[i] > logits[btix]) btix = i;
        idx[b] = bsix;
        idx[b + BB] = btix - 4;
    }
}

// ---------------------------------------------------------------------------
static void run_gemm2(hipStream_t stream,
    const u16* A, long long sAb,
    const u16* B, const int* bidx, long long sBexp,
    void* C, long long sCb, int ldc,
    const float* bias, long long sBiasExp,
    const void* resid, long long sResB, int ldr,
    int act, int N, int K, int outmode, int resmode)
{
    dim3 grid(N / 128, 8, BB);
    if (outmode == 1)
        gemm_bf16_kernel<1, 0><<<grid, 256, 0, stream>>>(A, sAb, B, bidx, sBexp,
            C, sCb, ldc, bias, sBiasExp, resid, sResB, ldr, act, N, K);
    else if (outmode == 2 && resmode == 0)
        gemm_bf16_kernel<2, 0><<<grid, 256, 0, stream>>>(A, sAb, B, bidx, sBexp,
            C, sCb, ldc, bias, sBiasExp, resid, sResB, ldr, act, N, K);
    else if (outmode == 2)
        gemm_bf16_kernel<2, 2><<<grid, 256, 0, stream>>>(A, sAb, B, bidx, sBexp,
            C, sCb, ldc, bias, sBiasExp, resid, sResB, ldr, act, N, K);
    else
        gemm_bf16_kernel<0, 1><<<grid, 256, 0, stream>>>(A, sAb, B, bidx, sBexp,
            C, sCb, ldc, bias, sBiasExp, resid, sResB, ldr, act, N, K);
}

extern "C" void kernel_launch(void* const* d_in, const int* in_sizes, int n_in,
                              void* d_out, int out_size, void* d_ws, size_t ws_size,
                              hipStream_t stream)
{
    const float* x       = (const float*)d_in[0];
    const float* rw1     = (const float*)d_in[1];
    const float* rb1     = (const float*)d_in[2];
    const float* rw2     = (const float*)d_in[3];
    const float* rb2     = (const float*)d_in[4];
    const float* gs      = (const float*)d_in[5];
    const float* bs      = (const float*)d_in[6];
    const float* gt      = (const float*)d_in[7];
    const float* btt     = (const float*)d_in[8];
    const float* gm      = (const float*)d_in[9];
    const float* bm      = (const float*)d_in[10];
    const float* sp_wqkv = (const float*)d_in[11];
    const float* sp_bqkv = (const float*)d_in[12];
    const float* sp_wo   = (const float*)d_in[13];
    const float* sp_bo   = (const float*)d_in[14];
    const float* tp_wq   = (const float*)d_in[15];
    const float* tp_bq   = (const float*)d_in[16];
    const float* tp_wk   = (const float*)d_in[17];
    const float* tp_bk   = (const float*)d_in[18];
    const float* tp_wv   = (const float*)d_in[19];
    const float* tp_bv   = (const float*)d_in[20];
    const float* tp_wo   = (const float*)d_in[21];
    const float* tp_bo   = (const float*)d_in[22];
    const float* c_wqkv  = (const float*)d_in[23];
    const float* c_bqkv  = (const float*)d_in[24];
    const float* c_wo    = (const float*)d_in[25];
    const float* c_bo    = (const float*)d_in[26];
    const float* m_w1    = (const float*)d_in[27];
    const float* m_b1    = (const float*)d_in[28];
    const float* m_w2    = (const float*)d_in[29];
    const float* m_b2    = (const float*)d_in[30];
    float* out = (float*)d_out;

    float* ws = (float*)d_ws;
    size_t o = 0;
    float* part  = ws + o; o += (size_t)BB * 8 * DD;
    int*   idx   = (int*)(ws + o); o += 16;
    float* tpb   = ws + o; o += 4 * 2304;                     // packed temporal bias
    float* x1b   = ws + o; o += (size_t)4096 * DD;            // f32 (x + fused)
    u16* xnb   = (u16*)(ws + o); o += (size_t)4096 * DD / 2;  // LN out (tiled bf16)
    u16* tmp1b = (u16*)(ws + o); o += (size_t)4096 * DD / 2;  // attn out (tiled)
    u16* tmp2b = (u16*)(ws + o); o += (size_t)4096 * DD / 2;  // LN for mlp (tiled)
    u16* soutb = (u16*)(ws + o); o += (size_t)4096 * DD / 2;  // spatial_out (tiled)
    u16* toutb = (u16*)(ws + o); o += (size_t)4096 * DD / 2;  // temporal_out (tiled)
    u16* qkvb  = (u16*)(ws + o); o += (size_t)4096 * 2304 / 2;// q|k|v row-major bf16
    u16* yb    = (u16*)(ws + o); o += (size_t)4096 * 3072 / 2;// mlp hidden (tiled)
    u16* wpool = (u16*)(ws + o); o += (size_t)CUM10 / 2;      // bf16 weights (tiled)

    u16* w_sp_qkv = wpool;
    u16* w_sp_wo  = wpool + CUM1;
    u16* w_tp_qkv = wpool + CUM2;   // interleaved [e][2304][768] tiled
    u16* w_tp_o   = wpool + CUM5;
    u16* w_c_qkv  = wpool + CUM6;
    u16* w_c_wo   = wpool + CUM7;
    u16* w_m1     = wpool + CUM8;
    u16* w_m2     = wpool + CUM9;

    int* idx_s = idx;
    int* idx_t = idx + BB;

    const long long sTD  = (long long)TT * DD;       // 512*768
    const long long sT3D = (long long)TT * 3 * DD;   // 512*2304
    const long long sT4D = (long long)TT * 4 * DD;   // 512*3072
    const float qk_scale = 1.0f / sqrtf((float)HDIM);

    // ---- weight convert (f32 -> bf16 tiled, coalesced-write transpose) ----
    cvt_kernel<<<3168, 256, 0, stream>>>(
        sp_wqkv, sp_wo, tp_wq, tp_wk, tp_wv, tp_wo, c_wqkv, c_wo, m_w1, m_w2, wpool);
    pack_tpb_kernel<<<36, 256, 0, stream>>>(tp_bq, tp_bk, tp_bv, tpb);

    // ---- router ----
    mean_part_kernel<<<dim3(BB, 3, 8), 256, 0, stream>>>(x, part);
    router_kernel<<<BB, 128, 0, stream>>>(part, rw1, rb1, rw2, rb2, idx);

    // ---- spatial branch ----
    ln_kernel<<<4096, 256, 0, stream>>>(x, gs, bs, xnb);
    // qkv = xn @ sp_wqkv[idx_s]^T + sp_bqkv[idx_s]  -> row-major for attn
    run_gemm2(stream, xnb, sTD, w_sp_qkv, idx_s, 3 * DDDD,
              qkvb, sT3D, 3 * DD, sp_bqkv, 3 * DD, nullptr, 0, 0,
              0, 3 * DD, DD, 1, 0);
    attn_kernel<<<dim3(TT / 64, BB * HH), 256, 0, stream>>>(qkvb, tmp1b, 0, qk_scale);
    // spatial_out = O @ sp_wo[idx_s]^T + sp_bo[idx_s]  -> tiled
    run_gemm2(stream, tmp1b, sTD, w_sp_wo, idx_s, DDDD,
              soutb, sTD, DD, sp_bo, DD, nullptr, 0, 0,
              0, DD, DD, 2, 0);

    // ---- temporal branch ----
    ln_kernel<<<4096, 256, 0, stream>>>(x, gt, btt, xnb);
    run_gemm2(stream, xnb, sTD, w_tp_qkv, idx_t, 3 * DDDD,
              qkvb, sT3D, 3 * DD, tpb, 3 * DD, nullptr, 0, 0,
              0, 3 * DD, DD, 1, 0);
    attn_kernel<<<dim3(TT / 64, BB * HH), 256, 0, stream>>>(qkvb, tmp1b, 1, qk_scale);
    // temporal_out = xt + O @ tp_wo[idx_t]^T + tp_bo[idx_t]  (tiled, tiled resid)
    run_gemm2(stream, tmp1b, sTD, w_tp_o, idx_t, DDDD,
              toutb, sTD, DD, tp_bo, DD, xnb, sTD, DD,
              0, DD, DD, 2, 2);

    // ---- cross attention ----
    run_gemm2(stream, soutb, sTD, w_c_qkv, nullptr, 0,
              qkvb, sT3D, 3 * DD, c_bqkv, 0, nullptr, 0, 0,
              0, DD, DD, 1, 0);
    // rows 768..2303 of c_wqkv = tiles 6.. -> offset DDDD elems
    run_gemm2(stream, toutb, sTD, w_c_qkv + DDDD, nullptr, 0,
              qkvb + DD, sT3D, 3 * DD, c_bqkv + DD, 0, nullptr, 0, 0,
              0, 2 * DD, DD, 1, 0);
    attn_kernel<<<dim3(TT / 64, BB * HH), 256, 0, stream>>>(qkvb, tmp1b, 0, qk_scale);
    // x1 = x + (fused_attn @ cross_wo^T + cross_bo)   (f32 out, f32 resid)
    run_gemm2(stream, tmp1b, sTD, w_c_wo, nullptr, 0,
              x1b, sTD, DD, c_bo, 0, x, sTD, DD,
              0, DD, DD, 0, 1);

    // ---- MLP ----
    ln_kernel<<<4096, 256, 0, stream>>>(x1b, gm, bm, tmp2b);
    // y = gelu(ln @ mlp_w1^T + b1) -> tiled bf16
    run_gemm2(stream, tmp2b, sTD, w_m1, nullptr, 0,
              yb, sT4D, 4 * DD, m_b1, 0, nullptr, 0, 0,
              1, 4 * DD, DD, 2, 0);
    // out = x1 + y @ mlp_w2^T + b2   (f32 out, f32 resid)
    run_gemm2(stream, yb, sT4D, w_m2, nullptr, 0,
              out, sTD, DD, m_b2, 0, x1b, sTD, DD,
              0, DD, 4 * DD, 0, 1);
}